// Round 11
// baseline (1546.270 us; speedup 1.0000x reference)
//
#include <hip/hip_runtime.h>
#include <stdint.h>

#define FD 128   // feature dim
#define NG 8     // graphs
#define NC 10    // classes
#define MAXB 1024           // max buckets (64 nodes each)
#define CHUNK 4096          // edges per counting chunk

typedef __attribute__((ext_vector_type(8))) short bf16x8;
typedef __attribute__((ext_vector_type(4))) float f32x4;
typedef __attribute__((ext_vector_type(2))) float f32x2;

__device__ __forceinline__ float bf2f(uint16_t u){
    union { uint32_t i; float f; } v; v.i = ((uint32_t)u) << 16; return v.f;
}
__device__ __forceinline__ uint16_t f2bf(float f){
    union { float f; uint32_t i; } v; v.f = f;
    uint32_t r = v.i + 0x7fff + ((v.i >> 16) & 1);
    return (uint16_t)(r >> 16);
}

// ---- fp8 e4m3 conversions (HW path with manual fallback) ----
#if __has_builtin(__builtin_amdgcn_cvt_pk_f32_fp8) && __has_builtin(__builtin_amdgcn_cvt_pk_fp8_f32)
__device__ __forceinline__ f32x2 fp8lo2f(uint32_t p){
    return __builtin_amdgcn_cvt_pk_f32_fp8((int)p, false);
}
__device__ __forceinline__ f32x2 fp8hi2f(uint32_t p){
    return __builtin_amdgcn_cvt_pk_f32_fp8((int)p, true);
}
__device__ __forceinline__ uint32_t pk4fp8(float a, float b, float c, float d){
    int u = 0;
    u = __builtin_amdgcn_cvt_pk_fp8_f32(a, b, u, false);
    u = __builtin_amdgcn_cvt_pk_fp8_f32(c, d, u, true);
    return (uint32_t)u;
}
#else
__device__ __forceinline__ float fp8tof(uint32_t b){
    union { uint32_t i; float f; } v;
    v.i = ((b & 0x7f) << 20) | ((b & 0x80) << 24);
    return v.f * 0x1p120f;
}
__device__ __forceinline__ f32x2 fp8lo2f(uint32_t p){
    return (f32x2){fp8tof(p & 0xff), fp8tof((p >> 8) & 0xff)};
}
__device__ __forceinline__ f32x2 fp8hi2f(uint32_t p){
    return (f32x2){fp8tof((p >> 16) & 0xff), fp8tof((p >> 24) & 0xff)};
}
__device__ __forceinline__ uint32_t f2fp8(float f){
    union { float f; uint32_t i; } v; v.f = f;
    uint32_t s = (v.i >> 24) & 0x80;
    float a = fabsf(f);
    if (a < 0x1p-10f) return s;
    if (a > 448.f) return s | 0x7e;
    v.f = a;
    uint32_t r = v.i + 0x7ffff + ((v.i >> 20) & 1);
    int e = (int)(r >> 23) - 127 + 7;
    uint32_t m = (r >> 20) & 7;
    if (e <= 0){
        uint32_t q = (uint32_t)(a * 512.f + 0.5f);
        return s | (q > 7 ? 8 : q);
    }
    if (e > 15) return s | 0x7e;
    return s | ((uint32_t)e << 3) | m;
}
__device__ __forceinline__ uint32_t pk4fp8(float a, float b, float c, float d){
    return (uint32_t)f2fp8(a) | ((uint32_t)f2fp8(b)<<8) |
           ((uint32_t)f2fp8(c)<<16) | ((uint32_t)f2fp8(d)<<24);
}
#endif

// ============ Fused: prep_w + per-chunk histograms + zero-init ============
__global__ __launch_bounds__(256) void k_prep(const float* __restrict__ W1,
        const float* __restrict__ W2, uint16_t* Wf1, uint16_t* Wf2,
        const int* __restrict__ ei, int E, int B, int C,
        int* __restrict__ cnt, float* __restrict__ pool,
        unsigned long long* __restrict__ state, int* __restrict__ counters){
    int t = threadIdx.x;
    if (blockIdx.x < 128){
        int id = blockIdx.x*256 + t;
        int w = id >> 14;
        int r = id & 16383;
        int j = r & 7, frag = r >> 3;
        int lane = frag & 63, t2 = frag >> 6;
        int n = t2 & 7, kk = t2 >> 3;
        int k = kk*32 + (lane>>4)*8 + j;
        int col = n*16 + (lane&15);
        float v = (w ? W2 : W1)[k*128 + col];
        (w ? Wf2 : Wf1)[r] = f2bf(v);
        if (blockIdx.x == 0){
            for (int i = t; i < NG*FD; i += 256) pool[i] = 0.f;
            for (int i = t; i < 1024; i += 256) state[i] = 0ull;
            if (t < 8) counters[t] = 0;
        }
        return;
    }
    __shared__ int hd[MAXB], hs[MAXB];
    int c = blockIdx.x - 128;
    for (int i=t;i<B;i+=256){ hd[i]=0; hs[i]=0; }
    __syncthreads();
    int e0 = c*CHUNK, e1 = min(E, e0+CHUNK);
    for (int e = e0+t; e < e1; e += 256){
        int s = ei[e], d = ei[E+e];
        atomicAdd(&hd[d>>6], 1);
        atomicAdd(&hs[s>>6], 1);
    }
    __syncthreads();
    for (int i=t;i<B;i+=256){
        cnt[(size_t)i*C + c]     = hd[i];
        cnt[(size_t)(B+i)*C + c] = hs[i];
    }
}

// ============ single-pass exclusive scan (decoupled lookback) ============
#define SEPT 16
#define STILE 4096
__global__ __launch_bounds__(256) void k_scan(int* __restrict__ a, int M,
        unsigned long long* __restrict__ state, int* __restrict__ ticket){
    __shared__ int bid_s, exc_s;
    __shared__ int s[256];
    int t = threadIdx.x;
    if (t == 0) bid_s = atomicAdd(ticket, 1);
    __syncthreads();
    int bid = bid_s;
    int base = bid*STILE + t*SEPT;
    int v[SEPT]; int sum = 0;
    #pragma unroll
    for (int i=0;i<SEPT;i++){ int idx=base+i; int x=(idx<M)?a[idx]:0; v[i]=sum; sum+=x; }
    s[t]=sum; __syncthreads();
    for (int o=1;o<256;o<<=1){ int x=(t>=o)?s[t-o]:0; __syncthreads(); s[t]+=x; __syncthreads(); }
    int tot = s[255];
    int te = s[t]-sum;
    if (t == 0){
        unsigned long long pub = ((bid==0) ? (2ull<<62) : (1ull<<62)) | (unsigned long long)(unsigned)tot;
        __hip_atomic_store(&state[bid], pub, __ATOMIC_RELEASE, __HIP_MEMORY_SCOPE_AGENT);
        int exc = 0;
        if (bid > 0){
            int p = bid-1;
            while (true){
                unsigned long long st = __hip_atomic_load(&state[p], __ATOMIC_ACQUIRE, __HIP_MEMORY_SCOPE_AGENT);
                unsigned long long fl = st >> 62;
                if (fl == 2ull){ exc += (int)(unsigned)st; break; }
                if (fl == 1ull){ exc += (int)(unsigned)st; p--; }
            }
            __hip_atomic_store(&state[bid],
                (2ull<<62) | (unsigned long long)(unsigned)(exc + tot),
                __ATOMIC_RELEASE, __HIP_MEMORY_SCOPE_AGENT);
        }
        exc_s = exc;
    }
    __syncthreads();
    int exc = exc_s;
    #pragma unroll
    for (int i=0;i<SEPT;i++){ int idx=base+i; if (idx<M) a[idx]=exc+te+v[i]; }
}

// ============ scatter edges: (dlocal,src) by dst bucket; src by src bucket ====
__global__ __launch_bounds__(256) void k_scatter(const int* __restrict__ ei, int E,
        int B, int C, const int* __restrict__ scan,
        uint32_t* __restrict__ tempD, uint16_t* __restrict__ tempS){
    __shared__ int cd[MAXB], cs[MAXB];
    int t = threadIdx.x, c = blockIdx.x;
    for (int i=t;i<B;i+=256){
        cd[i] = scan[(size_t)i*C + c];
        cs[i] = scan[(size_t)(B+i)*C + c] - E;
    }
    __syncthreads();
    int e0 = c*CHUNK, e1 = min(E, e0+CHUNK);
    for (int e = e0+t; e < e1; e += 256){
        int s = ei[e], d = ei[E+e];
        int p = atomicAdd(&cd[d>>6], 1);
        tempD[p] = ((uint32_t)(d & 63) << 20) | (uint32_t)s;
        int q = atomicAdd(&cs[s>>6], 1);
        tempS[q] = (uint16_t)s;
    }
}

// ============ per src-bucket: out-degree ============
__global__ __launch_bounds__(256) void k_degsrc(const uint16_t* __restrict__ tempS,
        const int* __restrict__ scan, int B, int C, int E, int N,
        int* __restrict__ deg_out){
    __shared__ int cnt[64];
    int b = blockIdx.x, t = threadIdx.x;
    int nb0 = b<<6;
    int sg0 = scan[(size_t)(B+b)*C] - E;
    int sg1 = ((b+1<B) ? scan[(size_t)(B+b+1)*C] : 2*E) - E;
    if (t<64) cnt[t]=0;
    __syncthreads();
    for (int i=sg0+t; i<sg1; i+=256)
        atomicAdd(&cnt[(int)tempS[i] - nb0], 1);
    __syncthreads();
    if (t<64){ int node=nb0+t; if (node<N) deg_out[node]=cnt[t]; }
}

// ============ GEMM (swapped-operand MFMA) -> split fp8 half-tables ============
__global__ __launch_bounds__(256) void k_gemm(const void* __restrict__ A,
        const uint16_t* __restrict__ Wf, const int* __restrict__ deg_out,
        uint8_t* __restrict__ outA, uint8_t* __restrict__ outB,
        int nrows, int amode){
    int t = threadIdx.x;
    int wave = t>>6, lane = t&63, quad = lane>>4, low = lane&15;

    int rowA  = blockIdx.x*64 + wave*16 + low;
    int rowAc = min(rowA, nrows-1);

    bf16x8 ah[4];
    if (amode){
        const uint16_t* arow = (const uint16_t*)A + (size_t)rowAc*FD;
        #pragma unroll
        for (int kk=0;kk<4;kk++)
            ah[kk] = *(const bf16x8*)(arow + kk*32 + quad*8);
    } else {
        const float* arow = (const float*)A + (size_t)rowAc*FD;
        #pragma unroll
        for (int kk=0;kk<4;kk++){
            f32x4 f0 = *(const f32x4*)(arow + kk*32 + quad*8);
            f32x4 f1 = *(const f32x4*)(arow + kk*32 + quad*8 + 4);
            #pragma unroll
            for (int j=0;j<4;j++) ah[kk][j]   = (short)f2bf(f0[j]);
            #pragma unroll
            for (int j=0;j<4;j++) ah[kk][j+4] = (short)f2bf(f1[j]);
        }
    }

    f32x4 acc[8];
    #pragma unroll
    for (int n=0;n<8;n++) acc[n] = (f32x4){0.f,0.f,0.f,0.f};

    #pragma unroll
    for (int kk=0;kk<4;kk++){
        #pragma unroll
        for (int n=0;n<8;n++){
            bf16x8 bh = *(const bf16x8*)(Wf + ((size_t)((kk*8+n)*64 + lane))*8);
            acc[n] = __builtin_amdgcn_mfma_f32_16x16x32_bf16(bh, ah[kk], acc[n], 0, 0, 0);
        }
    }

    if (rowA < nrows){
        float sc = rsqrtf((float)max(deg_out[rowA], 1));
        #pragma unroll
        for (int n=0;n<8;n++){
            uint32_t pk = pk4fp8(acc[n][0]*sc, acc[n][1]*sc, acc[n][2]*sc, acc[n][3]*sc);
            uint8_t* base = (n < 4) ? outA : outB;
            int cc = (n & 3)*16 + quad*4;
            *(uint32_t*)(base + (size_t)rowA*64 + cc) = pk;
        }
    }
}

// ============ SpMM half-pass: block per dst bucket, LDS accumulate ============
// tmp8h: N x 64 fp8 half-table (3.2 MB, L2-resident). Quarter-wave per edge,
// 4-deep batching. tempD stream: (dlocal<<20)|src, dst-bucket-grouped.
__global__ __launch_bounds__(256) void k_spmmb(const uint8_t* __restrict__ tmp8h,
        const uint32_t* __restrict__ tempD, const int* __restrict__ scan,
        int B, int C, int E, int N, const float* __restrict__ bias, int colbase,
        uint16_t* __restrict__ hout){
    __shared__ float acc[64*64];     // 16 KB
    __shared__ int indeg[64];
    int b = blockIdx.x, t = threadIdx.x;
    int nb0 = b<<6;
    for (int i=t;i<64*64;i+=256) acc[i]=0.f;
    if (t<64) indeg[t]=0;
    __syncthreads();
    int seg0 = scan[(size_t)b*C];
    int seg1 = scan[(size_t)(b+1)*C];      // == E for b==B-1
    int lane = t & 63, wv = t>>6;
    int l4 = lane & 15, q = lane >> 4;     // quarter-wave per edge
    const uint32_t* tp = (const uint32_t*)tmp8h;
    int per = ((seg1-seg0) + 3) >> 2;      // edges per wave (contiguous)
    int we0 = seg0 + wv*per, we1 = min(seg1, we0+per);
    for (int e = we0; e < we1; e += 16){
        uint32_t ed[4]; uint32_t p[4];
        #pragma unroll
        for (int k=0;k<4;k++){
            int ei = e + k*4 + q;
            ed[k] = (ei < we1) ? tempD[ei] : 0u;
        }
        #pragma unroll
        for (int k=0;k<4;k++)
            p[k] = tp[(size_t)(ed[k] & 0xFFFFFu)*16 + l4];
        #pragma unroll
        for (int k=0;k<4;k++){
            if (e + k*4 + q < we1){
                int dl = ed[k] >> 20;
                f32x2 v01 = fp8lo2f(p[k]), v23 = fp8hi2f(p[k]);
                float* a = &acc[dl*64 + l4*4];
                atomicAdd(a+0, v01.x);
                atomicAdd(a+1, v01.y);
                atomicAdd(a+2, v23.x);
                atomicAdd(a+3, v23.y);
                if (l4 == 0) atomicAdd(&indeg[dl], 1);
            }
        }
    }
    __syncthreads();
    for (int u = t; u < 64*32; u += 256){  // 64 nodes x 32 colpairs
        int nl = u>>5, cp = u&31;
        int node = nb0 + nl;
        if (node >= N) continue;
        float isq = rsqrtf((float)max(indeg[nl],1));
        float v0 = acc[nl*64 + cp*2]   * isq + bias[colbase + cp*2];
        float v1 = acc[nl*64 + cp*2+1] * isq + bias[colbase + cp*2+1];
        uint32_t o = (uint32_t)f2bf(fmaxf(v0,0.f)) | ((uint32_t)f2bf(fmaxf(v1,0.f)) << 16);
        __builtin_nontemporal_store(o, (uint32_t*)(hout + (size_t)node*FD + colbase + cp*2));
    }
}

// ============ pool: batched loads, run-length accumulate ============
__global__ __launch_bounds__(256) void k_pool(const uint16_t* __restrict__ h,
        const int* __restrict__ n2g, int N, float* __restrict__ pool){
    __shared__ float sacc[NG*FD];
    int t = threadIdx.x;
    for (int i = t; i < NG*FD; i += 256) sacc[i] = 0.f;
    __syncthreads();
    int fp = t & 63;
    int no = t >> 6;
    const uint32_t* hp = (const uint32_t*)h;
    int base = blockIdx.x * 64;
    int gg[16]; uint32_t pv[16];
    #pragma unroll
    for (int i = 0; i < 16; i++){
        int node = base + i*4 + no;
        int nc = min(node, N-1);
        gg[i] = n2g[nc];
        uint32_t v = hp[(size_t)nc*64 + fp];
        pv[i] = (node < N) ? v : 0u;
    }
    float r0 = 0.f, r1 = 0.f; int rg = gg[0];
    #pragma unroll
    for (int i = 0; i < 16; i++){
        if (gg[i] != rg){
            atomicAdd(&sacc[rg*FD + fp*2],     r0);
            atomicAdd(&sacc[rg*FD + fp*2 + 1], r1);
            r0 = r1 = 0.f; rg = gg[i];
        }
        r0 += bf2f((uint16_t)(pv[i] & 0xffff));
        r1 += bf2f((uint16_t)(pv[i] >> 16));
    }
    atomicAdd(&sacc[rg*FD + fp*2],     r0);
    atomicAdd(&sacc[rg*FD + fp*2 + 1], r1);
    __syncthreads();
    for (int i = t; i < NG*FD; i += 256){
        float v = sacc[i];
        if (v != 0.f) atomicAdd(&pool[i], v);
    }
}

// ============ mean, linear, softmax -> 80 f32 ============
__global__ __launch_bounds__(128) void k_final(const float* __restrict__ pool,
        const int* __restrict__ n2g, int N, const float* __restrict__ Wl,
        const float* __restrict__ bl, float* __restrict__ out){
    __shared__ int ub[NG+1];
    __shared__ float logits[NG][NC];
    int t = threadIdx.x;
    if (t <= NG){
        int lo = 0, hi = N;
        while (lo < hi){ int mid = (lo+hi)>>1; if (n2g[mid] < t) lo = mid+1; else hi = mid; }
        ub[t] = lo;
    }
    __syncthreads();
    if (t < NG*NC){
        int g = t/NC, c = t%NC;
        float cnt = (float)max(ub[g+1]-ub[g], 1);
        float inv = 1.f/cnt;
        float acc = bl[c];
        for (int d=0; d<FD; d++)
            acc += pool[g*FD+d]*inv * Wl[d*NC+c];
        logits[g][c] = acc;
    }
    __syncthreads();
    if (t < NG*NC){
        int g = t/NC, c = t%NC;
        float m = -1e30f;
        for (int i=0;i<NC;i++) m = fmaxf(m, logits[g][i]);
        float ssum = 0.f;
        for (int i=0;i<NC;i++) ssum += expf(logits[g][i]-m);
        out[t] = expf(logits[g][c]-m)/ssum;
    }
}

extern "C" void kernel_launch(void* const* d_in, const int* in_sizes, int n_in,
                              void* d_out, int out_size, void* d_ws, size_t ws_size,
                              hipStream_t stream) {
    const float* x   = (const float*)d_in[0];
    const int*   ei  = (const int*)d_in[1];
    const int*   n2g = (const int*)d_in[2];
    const float* W1  = (const float*)d_in[3];
    const float* b1  = (const float*)d_in[4];
    const float* W2  = (const float*)d_in[5];
    const float* b2  = (const float*)d_in[6];
    const float* Wl  = (const float*)d_in[7];
    const float* bl  = (const float*)d_in[8];
    float* outp = (float*)d_out;

    int N = in_sizes[2];
    int E = in_sizes[1] / 2;

    int B = (N + 63) >> 6;                 // 64-node buckets (N < 65536)
    int C = (E + CHUNK - 1) / CHUNK;
    int M = 2*B*C;
    int nscan = (M + STILE - 1) / STILE;   // <= 1024

    char* w = (char*)d_ws;
    size_t off = 0;
    auto alloc = [&](size_t bytes)->char*{ char* p = w + off; off += (bytes + 255) & ~(size_t)255; return p; };
    float*    pool    = (float*)alloc((size_t)NG*FD*4);
    unsigned long long* state = (unsigned long long*)alloc(1024*8);
    int*      counters= (int*)alloc(8*4);
    int*      deg_out = (int*)alloc((size_t)N*4);
    int*      cnt     = (int*)alloc((size_t)M*4);        // lives until last spmmb
    uint16_t* Wf1     = (uint16_t*)alloc(16384*2);
    uint16_t* Wf2     = (uint16_t*)alloc(16384*2);
    uint8_t*  tmp8A   = (uint8_t*)alloc((size_t)N*64);   // fp8 half-tables
    uint8_t*  tmp8B   = (uint8_t*)alloc((size_t)N*64);
    uint32_t* tempD   = (uint32_t*)alloc((size_t)E*4);   // lives until last spmmb
    uint16_t* hb      = (uint16_t*)alloc((size_t)N*FD*2);
    (void)ws_size;
    uint16_t* tempS = (uint16_t*)hb;                     // alias: dead before hb written

    k_prep   <<<128 + C, 256, 0, stream>>>(W1, W2, Wf1, Wf2, ei, E, B, C,
                                           cnt, pool, state, counters);
    k_scan   <<<nscan, 256, 0, stream>>>(cnt, M, state, &counters[0]);
    k_scatter<<<C, 256, 0, stream>>>(ei, E, B, C, cnt, tempD, tempS);
    k_degsrc <<<B, 256, 0, stream>>>(tempS, cnt, B, C, E, N, deg_out);

    int gb = (N + 63)/64;
    int pb = (N + 63)/64;
    k_gemm  <<<gb, 256, 0, stream>>>(x,  Wf1, deg_out, tmp8A, tmp8B, N, 0);
    k_spmmb <<<B, 256, 0, stream>>>(tmp8A, tempD, cnt, B, C, E, N, b1, 0,  hb);
    k_spmmb <<<B, 256, 0, stream>>>(tmp8B, tempD, cnt, B, C, E, N, b1, 64, hb);
    k_gemm  <<<gb, 256, 0, stream>>>(hb, Wf2, deg_out, tmp8A, tmp8B, N, 1);
    k_spmmb <<<B, 256, 0, stream>>>(tmp8A, tempD, cnt, B, C, E, N, b2, 0,  hb);
    k_spmmb <<<B, 256, 0, stream>>>(tmp8B, tempD, cnt, B, C, E, N, b2, 64, hb);
    k_pool  <<<pb, 256, 0, stream>>>(hb, n2g, N, pool);
    k_final <<<1,  128, 0, stream>>>(pool, n2g, N, Wl, bl, outp);
}

// Round 12
// 258.172 us; speedup vs baseline: 5.9893x; 5.9893x over previous
//
#include <hip/hip_runtime.h>
#include <stdint.h>

#define FD 128   // feature dim
#define NG 8     // graphs
#define NC 10    // classes
#define MAXB 1024           // max buckets
#define CHUNK 4096          // edges per counting chunk

typedef __attribute__((ext_vector_type(8))) short bf16x8;
typedef __attribute__((ext_vector_type(4))) float f32x4;
typedef __attribute__((ext_vector_type(2))) float f32x2;

__device__ __forceinline__ float bf2f(uint16_t u){
    union { uint32_t i; float f; } v; v.i = ((uint32_t)u) << 16; return v.f;
}
__device__ __forceinline__ uint16_t f2bf(float f){
    union { float f; uint32_t i; } v; v.f = f;
    uint32_t r = v.i + 0x7fff + ((v.i >> 16) & 1);
    return (uint16_t)(r >> 16);
}

// ---- fp8 e4m3 conversions (HW path with manual fallback) ----
#if __has_builtin(__builtin_amdgcn_cvt_pk_f32_fp8) && __has_builtin(__builtin_amdgcn_cvt_pk_fp8_f32)
__device__ __forceinline__ f32x2 fp8lo2f(uint32_t p){
    return __builtin_amdgcn_cvt_pk_f32_fp8((int)p, false);
}
__device__ __forceinline__ f32x2 fp8hi2f(uint32_t p){
    return __builtin_amdgcn_cvt_pk_f32_fp8((int)p, true);
}
__device__ __forceinline__ uint32_t pk4fp8(float a, float b, float c, float d){
    int u = 0;
    u = __builtin_amdgcn_cvt_pk_fp8_f32(a, b, u, false);
    u = __builtin_amdgcn_cvt_pk_fp8_f32(c, d, u, true);
    return (uint32_t)u;
}
#else
__device__ __forceinline__ float fp8tof(uint32_t b){
    union { uint32_t i; float f; } v;
    v.i = ((b & 0x7f) << 20) | ((b & 0x80) << 24);
    return v.f * 0x1p120f;
}
__device__ __forceinline__ f32x2 fp8lo2f(uint32_t p){
    return (f32x2){fp8tof(p & 0xff), fp8tof((p >> 8) & 0xff)};
}
__device__ __forceinline__ f32x2 fp8hi2f(uint32_t p){
    return (f32x2){fp8tof((p >> 16) & 0xff), fp8tof((p >> 24) & 0xff)};
}
__device__ __forceinline__ uint32_t f2fp8(float f){
    union { float f; uint32_t i; } v; v.f = f;
    uint32_t s = (v.i >> 24) & 0x80;
    float a = fabsf(f);
    if (a < 0x1p-10f) return s;
    if (a > 448.f) return s | 0x7e;
    v.f = a;
    uint32_t r = v.i + 0x7ffff + ((v.i >> 20) & 1);
    int e = (int)(r >> 23) - 127 + 7;
    uint32_t m = (r >> 20) & 7;
    if (e <= 0){
        uint32_t q = (uint32_t)(a * 512.f + 0.5f);
        return s | (q > 7 ? 8 : q);
    }
    if (e > 15) return s | 0x7e;
    return s | ((uint32_t)e << 3) | m;
}
__device__ __forceinline__ uint32_t pk4fp8(float a, float b, float c, float d){
    return (uint32_t)f2fp8(a) | ((uint32_t)f2fp8(b)<<8) |
           ((uint32_t)f2fp8(c)<<16) | ((uint32_t)f2fp8(d)<<24);
}
#endif

// ============ Fused: prep_w + per-chunk histograms + zero-init ============
__global__ __launch_bounds__(256) void k_prep(const float* __restrict__ W1,
        const float* __restrict__ W2, uint16_t* Wf1, uint16_t* Wf2,
        const int* __restrict__ ei, int E, int B, int C, int shift,
        int* __restrict__ cnt, float* __restrict__ pool,
        unsigned long long* __restrict__ state, int* __restrict__ counters){
    int t = threadIdx.x;
    if (blockIdx.x < 128){
        int id = blockIdx.x*256 + t;
        int w = id >> 14;
        int r = id & 16383;
        int j = r & 7, frag = r >> 3;
        int lane = frag & 63, t2 = frag >> 6;
        int n = t2 & 7, kk = t2 >> 3;
        int k = kk*32 + (lane>>4)*8 + j;
        int col = n*16 + (lane&15);
        float v = (w ? W2 : W1)[k*128 + col];
        (w ? Wf2 : Wf1)[r] = f2bf(v);
        if (blockIdx.x == 0){
            for (int i = t; i < NG*FD; i += 256) pool[i] = 0.f;
            for (int i = t; i < 1024; i += 256) state[i] = 0ull;
            if (t < 8) counters[t] = 0;
        }
        return;
    }
    __shared__ int hd[MAXB], hs[MAXB];
    int c = blockIdx.x - 128;
    for (int i=t;i<B;i+=256){ hd[i]=0; hs[i]=0; }
    __syncthreads();
    int e0 = c*CHUNK, e1 = min(E, e0+CHUNK);
    for (int e = e0+t; e < e1; e += 256){
        int s = ei[e], d = ei[E+e];
        atomicAdd(&hd[d>>shift], 1);
        atomicAdd(&hs[s>>shift], 1);
    }
    __syncthreads();
    for (int i=t;i<B;i+=256){
        cnt[(size_t)i*C + c]     = hd[i];
        cnt[(size_t)(B+i)*C + c] = hs[i];
    }
}

// ============ single-pass exclusive scan (decoupled lookback) ============
#define SEPT 16
#define STILE 4096
__global__ __launch_bounds__(256) void k_scan(int* __restrict__ a, int M,
        unsigned long long* __restrict__ state, int* __restrict__ ticket){
    __shared__ int bid_s, exc_s;
    __shared__ int s[256];
    int t = threadIdx.x;
    if (t == 0) bid_s = atomicAdd(ticket, 1);
    __syncthreads();
    int bid = bid_s;
    int base = bid*STILE + t*SEPT;
    int v[SEPT]; int sum = 0;
    #pragma unroll
    for (int i=0;i<SEPT;i++){ int idx=base+i; int x=(idx<M)?a[idx]:0; v[i]=sum; sum+=x; }
    s[t]=sum; __syncthreads();
    for (int o=1;o<256;o<<=1){ int x=(t>=o)?s[t-o]:0; __syncthreads(); s[t]+=x; __syncthreads(); }
    int tot = s[255];
    int te = s[t]-sum;
    if (t == 0){
        unsigned long long pub = ((bid==0) ? (2ull<<62) : (1ull<<62)) | (unsigned long long)(unsigned)tot;
        __hip_atomic_store(&state[bid], pub, __ATOMIC_RELEASE, __HIP_MEMORY_SCOPE_AGENT);
        int exc = 0;
        if (bid > 0){
            int p = bid-1;
            while (true){
                unsigned long long st = __hip_atomic_load(&state[p], __ATOMIC_ACQUIRE, __HIP_MEMORY_SCOPE_AGENT);
                unsigned long long fl = st >> 62;
                if (fl == 2ull){ exc += (int)(unsigned)st; break; }
                if (fl == 1ull){ exc += (int)(unsigned)st; p--; }
            }
            __hip_atomic_store(&state[bid],
                (2ull<<62) | (unsigned long long)(unsigned)(exc + tot),
                __ATOMIC_RELEASE, __HIP_MEMORY_SCOPE_AGENT);
        }
        exc_s = exc;
    }
    __syncthreads();
    int exc = exc_s;
    #pragma unroll
    for (int i=0;i<SEPT;i++){ int idx=base+i; if (idx<M) a[idx]=exc+te+v[i]; }
}

// ============ scatter edges into bucket-grouped temps ============
__global__ __launch_bounds__(256) void k_scatter(const int* __restrict__ ei, int E,
        int B, int C, int shift, const int* __restrict__ scan,
        uint32_t* __restrict__ tempD, uint16_t* __restrict__ tempS){
    __shared__ int cd[MAXB], cs[MAXB];
    int t = threadIdx.x, c = blockIdx.x;
    for (int i=t;i<B;i+=256){
        cd[i] = scan[(size_t)i*C + c];
        cs[i] = scan[(size_t)(B+i)*C + c] - E;
    }
    __syncthreads();
    int e0 = c*CHUNK, e1 = min(E, e0+CHUNK);
    int lmask = (1<<shift) - 1;
    for (int e = e0+t; e < e1; e += 256){
        int s = ei[e], d = ei[E+e];
        int p = atomicAdd(&cd[d>>shift], 1);
        tempD[p] = ((uint32_t)(d & lmask) << 20) | (uint32_t)s;
        int q = atomicAdd(&cs[s>>shift], 1);
        tempS[q] = (uint16_t)s;
    }
}

// ============ per-bucket: row_off + csr (dst) and deg_out (src) ============
__global__ __launch_bounds__(256) void k_build2(const uint32_t* __restrict__ tempD,
        const uint16_t* __restrict__ tempS, const int* __restrict__ scan,
        int B, int C, int shift, int E, int N,
        int* __restrict__ row_off, int* __restrict__ csr, int* __restrict__ deg_out){
    __shared__ int cnt[MAXB];
    __shared__ int offl[MAXB];
    int b = blockIdx.x, t = threadIdx.x;
    int range = 1<<shift, nb0 = b<<shift;
    int seg0 = scan[(size_t)b*C];
    int seg1 = (b+1<B) ? scan[(size_t)(b+1)*C] : E;
    for (int i=t;i<range;i+=256) cnt[i]=0;
    __syncthreads();
    for (int i=seg0+t; i<seg1; i+=256)
        atomicAdd(&cnt[tempD[i]>>20], 1);
    __syncthreads();
    if (t==0){ int run=0; for (int i=0;i<range;i++){ offl[i]=run; run+=cnt[i]; } }
    __syncthreads();
    for (int i=t;i<range;i+=256){
        int node = nb0+i;
        if (node < N) row_off[node] = seg0 + offl[i];
    }
    if (b==B-1 && t==0) row_off[N] = E;
    for (int i=t;i<range;i+=256) cnt[i] = offl[i];
    __syncthreads();
    for (int i=seg0+t; i<seg1; i+=256){
        uint32_t v = tempD[i];
        int p = atomicAdd(&cnt[v>>20], 1);
        csr[seg0 + p] = (int)(v & 0xFFFFFu);
    }
    __syncthreads();
    int sg0 = scan[(size_t)(B+b)*C] - E;
    int sg1 = ((b+1<B) ? scan[(size_t)(B+b+1)*C] : 2*E) - E;
    for (int i=t;i<range;i+=256) cnt[i]=0;
    __syncthreads();
    for (int i=sg0+t; i<sg1; i+=256)
        atomicAdd(&cnt[(int)tempS[i] - nb0], 1);
    __syncthreads();
    for (int i=t;i<range;i+=256){
        int node = nb0+i;
        if (node < N) deg_out[node] = cnt[i];
    }
}

// ============ GEMM (swapped-operand MFMA) -> split fp8 half-tables ============
__global__ __launch_bounds__(256) void k_gemm(const void* __restrict__ A,
        const uint16_t* __restrict__ Wf, const int* __restrict__ deg_out,
        uint8_t* __restrict__ outA, uint8_t* __restrict__ outB,
        int nrows, int amode){
    int t = threadIdx.x;
    int wave = t>>6, lane = t&63, quad = lane>>4, low = lane&15;

    int rowA  = blockIdx.x*64 + wave*16 + low;
    int rowAc = min(rowA, nrows-1);

    bf16x8 ah[4];
    if (amode){
        const uint16_t* arow = (const uint16_t*)A + (size_t)rowAc*FD;
        #pragma unroll
        for (int kk=0;kk<4;kk++)
            ah[kk] = *(const bf16x8*)(arow + kk*32 + quad*8);
    } else {
        const float* arow = (const float*)A + (size_t)rowAc*FD;
        #pragma unroll
        for (int kk=0;kk<4;kk++){
            f32x4 f0 = *(const f32x4*)(arow + kk*32 + quad*8);
            f32x4 f1 = *(const f32x4*)(arow + kk*32 + quad*8 + 4);
            #pragma unroll
            for (int j=0;j<4;j++) ah[kk][j]   = (short)f2bf(f0[j]);
            #pragma unroll
            for (int j=0;j<4;j++) ah[kk][j+4] = (short)f2bf(f1[j]);
        }
    }

    f32x4 acc[8];
    #pragma unroll
    for (int n=0;n<8;n++) acc[n] = (f32x4){0.f,0.f,0.f,0.f};

    #pragma unroll
    for (int kk=0;kk<4;kk++){
        #pragma unroll
        for (int n=0;n<8;n++){
            bf16x8 bh = *(const bf16x8*)(Wf + ((size_t)((kk*8+n)*64 + lane))*8);
            acc[n] = __builtin_amdgcn_mfma_f32_16x16x32_bf16(bh, ah[kk], acc[n], 0, 0, 0);
        }
    }

    if (rowA < nrows){
        float sc = rsqrtf((float)max(deg_out[rowA], 1));
        #pragma unroll
        for (int n=0;n<8;n++){
            uint32_t pk = pk4fp8(acc[n][0]*sc, acc[n][1]*sc, acc[n][2]*sc, acc[n][3]*sc);
            uint8_t* base = (n < 4) ? outA : outB;
            int cc = (n & 3)*16 + quad*4;
            *(uint32_t*)(base + (size_t)rowA*64 + cc) = pk;
        }
    }
}

// ============ SpMM half-pass: wave per node, quarter-wave per edge ============
// tmp8h: N x 64 fp8 half-table (3.2 MB, fits per-XCD L2). 4 edges/step, 4
// loads always in flight (clamped indices, masked accumulate). Register
// accumulate + cross-quarter shfl reduce.
__global__ __launch_bounds__(256) void k_spmm(const uint8_t* __restrict__ tmp8h,
        const int* __restrict__ row_off, const int* __restrict__ csr_src,
        const float* __restrict__ bias, int colbase,
        uint16_t* __restrict__ hout, int N){
    int node = blockIdx.x*4 + (threadIdx.x>>6);
    int lane = threadIdx.x & 63;
    int l4 = lane & 15, q = lane >> 4;
    if (node >= N) return;
    int e0 = row_off[node], e1 = row_off[node+1];
    const uint32_t* tp = (const uint32_t*)tmp8h;
    f32x2 a01 = {0.f,0.f}, a23 = {0.f,0.f};
    for (int base = e0; base < e1; base += 64){
        int my = 0;
        if (base + lane < e1) my = csr_src[base + lane];
        int cnt = min(64, e1 - base);
        for (int j = 0; j < cnt; j += 16){
            int i0 = j + q, i1 = j + 4 + q, i2 = j + 8 + q, i3 = j + 12 + q;
            int s0 = __shfl(my, min(i0, cnt-1));
            int s1 = __shfl(my, min(i1, cnt-1));
            int s2 = __shfl(my, min(i2, cnt-1));
            int s3 = __shfl(my, min(i3, cnt-1));
            uint32_t p0 = tp[(size_t)s0*16 + l4];
            uint32_t p1 = tp[(size_t)s1*16 + l4];
            uint32_t p2 = tp[(size_t)s2*16 + l4];
            uint32_t p3 = tp[(size_t)s3*16 + l4];
            if (i0 < cnt){ a01 += fp8lo2f(p0); a23 += fp8hi2f(p0); }
            if (i1 < cnt){ a01 += fp8lo2f(p1); a23 += fp8hi2f(p1); }
            if (i2 < cnt){ a01 += fp8lo2f(p2); a23 += fp8hi2f(p2); }
            if (i3 < cnt){ a01 += fp8lo2f(p3); a23 += fp8hi2f(p3); }
        }
    }
    // combine quarters (lanes sharing l4 hold the same 4 columns)
    a01.x += __shfl_xor(a01.x, 16); a01.x += __shfl_xor(a01.x, 32);
    a01.y += __shfl_xor(a01.y, 16); a01.y += __shfl_xor(a01.y, 32);
    a23.x += __shfl_xor(a23.x, 16); a23.x += __shfl_xor(a23.x, 32);
    a23.y += __shfl_xor(a23.y, 16); a23.y += __shfl_xor(a23.y, 32);
    if (q == 0){
        float isq = rsqrtf((float)max(e1 - e0, 1));
        f32x4 bs = *(const f32x4*)(bias + colbase + l4*4);
        float r0 = fmaxf(a01.x*isq + bs[0], 0.f);
        float r1 = fmaxf(a01.y*isq + bs[1], 0.f);
        float r2 = fmaxf(a23.x*isq + bs[2], 0.f);
        float r3 = fmaxf(a23.y*isq + bs[3], 0.f);
        uint2 o;
        o.x = (uint32_t)f2bf(r0) | ((uint32_t)f2bf(r1) << 16);
        o.y = (uint32_t)f2bf(r2) | ((uint32_t)f2bf(r3) << 16);
        *(uint2*)(hout + (size_t)node*FD + colbase + l4*4) = o;
    }
}

// ============ pool: batched loads, run-length accumulate ============
__global__ __launch_bounds__(256) void k_pool(const uint16_t* __restrict__ h,
        const int* __restrict__ n2g, int N, float* __restrict__ pool){
    __shared__ float sacc[NG*FD];
    int t = threadIdx.x;
    for (int i = t; i < NG*FD; i += 256) sacc[i] = 0.f;
    __syncthreads();
    int fp = t & 63;
    int no = t >> 6;
    const uint32_t* hp = (const uint32_t*)h;
    int base = blockIdx.x * 64;
    int gg[16]; uint32_t pv[16];
    #pragma unroll
    for (int i = 0; i < 16; i++){
        int node = base + i*4 + no;
        int nc = min(node, N-1);
        gg[i] = n2g[nc];
        uint32_t v = hp[(size_t)nc*64 + fp];
        pv[i] = (node < N) ? v : 0u;
    }
    float r0 = 0.f, r1 = 0.f; int rg = gg[0];
    #pragma unroll
    for (int i = 0; i < 16; i++){
        if (gg[i] != rg){
            atomicAdd(&sacc[rg*FD + fp*2],     r0);
            atomicAdd(&sacc[rg*FD + fp*2 + 1], r1);
            r0 = r1 = 0.f; rg = gg[i];
        }
        r0 += bf2f((uint16_t)(pv[i] & 0xffff));
        r1 += bf2f((uint16_t)(pv[i] >> 16));
    }
    atomicAdd(&sacc[rg*FD + fp*2],     r0);
    atomicAdd(&sacc[rg*FD + fp*2 + 1], r1);
    __syncthreads();
    for (int i = t; i < NG*FD; i += 256){
        float v = sacc[i];
        if (v != 0.f) atomicAdd(&pool[i], v);
    }
}

// ============ mean, linear, softmax -> 80 f32 ============
__global__ __launch_bounds__(128) void k_final(const float* __restrict__ pool,
        const int* __restrict__ n2g, int N, const float* __restrict__ Wl,
        const float* __restrict__ bl, float* __restrict__ out){
    __shared__ int ub[NG+1];
    __shared__ float logits[NG][NC];
    int t = threadIdx.x;
    if (t <= NG){
        int lo = 0, hi = N;
        while (lo < hi){ int mid = (lo+hi)>>1; if (n2g[mid] < t) lo = mid+1; else hi = mid; }
        ub[t] = lo;
    }
    __syncthreads();
    if (t < NG*NC){
        int g = t/NC, c = t%NC;
        float cnt = (float)max(ub[g+1]-ub[g], 1);
        float inv = 1.f/cnt;
        float acc = bl[c];
        for (int d=0; d<FD; d++)
            acc += pool[g*FD+d]*inv * Wl[d*NC+c];
        logits[g][c] = acc;
    }
    __syncthreads();
    if (t < NG*NC){
        int g = t/NC, c = t%NC;
        float m = -1e30f;
        for (int i=0;i<NC;i++) m = fmaxf(m, logits[g][i]);
        float ssum = 0.f;
        for (int i=0;i<NC;i++) ssum += expf(logits[g][i]-m);
        out[t] = expf(logits[g][c]-m)/ssum;
    }
}

extern "C" void kernel_launch(void* const* d_in, const int* in_sizes, int n_in,
                              void* d_out, int out_size, void* d_ws, size_t ws_size,
                              hipStream_t stream) {
    const float* x   = (const float*)d_in[0];
    const int*   ei  = (const int*)d_in[1];
    const int*   n2g = (const int*)d_in[2];
    const float* W1  = (const float*)d_in[3];
    const float* b1  = (const float*)d_in[4];
    const float* W2  = (const float*)d_in[5];
    const float* b2  = (const float*)d_in[6];
    const float* Wl  = (const float*)d_in[7];
    const float* bl  = (const float*)d_in[8];
    float* outp = (float*)d_out;

    int N = in_sizes[2];
    int E = in_sizes[1] / 2;

    int shift = 6;
    while ((((N + (1<<shift) - 1) >> shift) > MAXB) && shift < 10) shift++;
    int B = (N + (1<<shift) - 1) >> shift;
    int C = (E + CHUNK - 1) / CHUNK;
    int M = 2*B*C;
    int nscan = (M + STILE - 1) / STILE;   // <= 1024 (state array)

    char* w = (char*)d_ws;
    size_t off = 0;
    auto alloc = [&](size_t bytes)->char*{ char* p = w + off; off += (bytes + 255) & ~(size_t)255; return p; };
    float*    pool    = (float*)alloc((size_t)NG*FD*4);
    unsigned long long* state = (unsigned long long*)alloc(1024*8);
    int*      counters= (int*)alloc(8*4);       // [0]=scan ticket
    int*      deg_out = (int*)alloc((size_t)N*4);
    int*      row_off = (int*)alloc((size_t)(N+1)*4);
    int*      csr     = (int*)alloc((size_t)E*4);
    uint16_t* Wf1     = (uint16_t*)alloc(16384*2);
    uint16_t* Wf2     = (uint16_t*)alloc(16384*2);
    uint8_t*  tmp8A   = (uint8_t*)alloc((size_t)N*64);   // fp8 half-tables
    uint8_t*  tmp8B   = (uint8_t*)alloc((size_t)N*64);
    uint16_t* hb      = (uint16_t*)alloc((size_t)N*FD*2);
    (void)ws_size;
    // aliases (live only during CSR build, before tmp8/hb are written)
    uint32_t* tempD = (uint32_t*)tmp8A;                  // E*4 <= N*64
    uint16_t* tempS = (uint16_t*)tmp8B;                  // E*2 <= N*64
    int* cnt = (int*)hb;                                 // M*4 <= N*FD*2

    k_prep   <<<128 + C, 256, 0, stream>>>(W1, W2, Wf1, Wf2, ei, E, B, C, shift,
                                           cnt, pool, state, counters);
    k_scan   <<<nscan, 256, 0, stream>>>(cnt, M, state, &counters[0]);
    k_scatter<<<C, 256, 0, stream>>>(ei, E, B, C, shift, cnt, tempD, tempS);
    k_build2 <<<B, 256, 0, stream>>>(tempD, tempS, cnt, B, C, shift, E, N, row_off, csr, deg_out);

    int gb = (N + 63)/64;
    int sb = (N + 3)/4;
    int pb = (N + 63)/64;
    k_gemm <<<gb, 256, 0, stream>>>(x,  Wf1, deg_out, tmp8A, tmp8B, N, 0);
    k_spmm <<<sb, 256, 0, stream>>>(tmp8A, row_off, csr, b1, 0,  hb, N);
    k_spmm <<<sb, 256, 0, stream>>>(tmp8B, row_off, csr, b1, 64, hb, N);
    k_gemm <<<gb, 256, 0, stream>>>(hb, Wf2, deg_out, tmp8A, tmp8B, N, 1);
    k_spmm <<<sb, 256, 0, stream>>>(tmp8A, row_off, csr, b2, 0,  hb, N);
    k_spmm <<<sb, 256, 0, stream>>>(tmp8B, row_off, csr, b2, 64, hb, N);
    k_pool <<<pb, 256, 0, stream>>>(hb, n2g, N, pool);
    k_final<<<1,  128, 0, stream>>>(pool, n2g, N, Wl, bl, outp);
}

// Round 13
// 231.335 us; speedup vs baseline: 6.6841x; 1.1160x over previous
//
#include <hip/hip_runtime.h>
#include <stdint.h>

#define FD 128   // feature dim
#define NG 8     // graphs
#define NC 10    // classes
#define MAXB 1024           // max buckets
#define CHUNK 4096          // edges per counting chunk

typedef __attribute__((ext_vector_type(8))) short bf16x8;
typedef __attribute__((ext_vector_type(4))) float f32x4;
typedef __attribute__((ext_vector_type(2))) float f32x2;

__device__ __forceinline__ float bf2f(uint16_t u){
    union { uint32_t i; float f; } v; v.i = ((uint32_t)u) << 16; return v.f;
}
__device__ __forceinline__ uint16_t f2bf(float f){
    union { float f; uint32_t i; } v; v.f = f;
    uint32_t r = v.i + 0x7fff + ((v.i >> 16) & 1);
    return (uint16_t)(r >> 16);
}

// ---- fp8 e4m3 conversions (HW path with manual fallback) ----
#if __has_builtin(__builtin_amdgcn_cvt_pk_f32_fp8) && __has_builtin(__builtin_amdgcn_cvt_pk_fp8_f32)
__device__ __forceinline__ f32x2 fp8lo2f(uint32_t p){
    return __builtin_amdgcn_cvt_pk_f32_fp8((int)p, false);
}
__device__ __forceinline__ f32x2 fp8hi2f(uint32_t p){
    return __builtin_amdgcn_cvt_pk_f32_fp8((int)p, true);
}
__device__ __forceinline__ uint32_t pk4fp8(float a, float b, float c, float d){
    int u = 0;
    u = __builtin_amdgcn_cvt_pk_fp8_f32(a, b, u, false);
    u = __builtin_amdgcn_cvt_pk_fp8_f32(c, d, u, true);
    return (uint32_t)u;
}
#else
__device__ __forceinline__ float fp8tof(uint32_t b){
    union { uint32_t i; float f; } v;
    v.i = ((b & 0x7f) << 20) | ((b & 0x80) << 24);
    return v.f * 0x1p120f;
}
__device__ __forceinline__ f32x2 fp8lo2f(uint32_t p){
    return (f32x2){fp8tof(p & 0xff), fp8tof((p >> 8) & 0xff)};
}
__device__ __forceinline__ f32x2 fp8hi2f(uint32_t p){
    return (f32x2){fp8tof((p >> 16) & 0xff), fp8tof((p >> 24) & 0xff)};
}
__device__ __forceinline__ uint32_t f2fp8(float f){
    union { float f; uint32_t i; } v; v.f = f;
    uint32_t s = (v.i >> 24) & 0x80;
    float a = fabsf(f);
    if (a < 0x1p-10f) return s;
    if (a > 448.f) return s | 0x7e;
    v.f = a;
    uint32_t r = v.i + 0x7ffff + ((v.i >> 20) & 1);
    int e = (int)(r >> 23) - 127 + 7;
    uint32_t m = (r >> 20) & 7;
    if (e <= 0){
        uint32_t q = (uint32_t)(a * 512.f + 0.5f);
        return s | (q > 7 ? 8 : q);
    }
    if (e > 15) return s | 0x7e;
    return s | ((uint32_t)e << 3) | m;
}
__device__ __forceinline__ uint32_t pk4fp8(float a, float b, float c, float d){
    return (uint32_t)f2fp8(a) | ((uint32_t)f2fp8(b)<<8) |
           ((uint32_t)f2fp8(c)<<16) | ((uint32_t)f2fp8(d)<<24);
}
#endif

// ============ Fused: prep_w + per-chunk histograms + zero-init ============
__global__ __launch_bounds__(256) void k_prep(const float* __restrict__ W1,
        const float* __restrict__ W2, uint16_t* Wf1, uint16_t* Wf2,
        const int* __restrict__ ei, int E, int B, int C, int shift,
        int* __restrict__ cnt, float* __restrict__ pool,
        unsigned long long* __restrict__ state, int* __restrict__ counters){
    int t = threadIdx.x;
    if (blockIdx.x < 128){
        int id = blockIdx.x*256 + t;
        int w = id >> 14;
        int r = id & 16383;
        int j = r & 7, frag = r >> 3;
        int lane = frag & 63, t2 = frag >> 6;
        int n = t2 & 7, kk = t2 >> 3;
        int k = kk*32 + (lane>>4)*8 + j;
        int col = n*16 + (lane&15);
        float v = (w ? W2 : W1)[k*128 + col];
        (w ? Wf2 : Wf1)[r] = f2bf(v);
        if (blockIdx.x == 0){
            for (int i = t; i < NG*FD; i += 256) pool[i] = 0.f;
            for (int i = t; i < 1024; i += 256) state[i] = 0ull;
            if (t < 8) counters[t] = 0;
        }
        return;
    }
    __shared__ int hd[MAXB], hs[MAXB];
    int c = blockIdx.x - 128;
    for (int i=t;i<B;i+=256){ hd[i]=0; hs[i]=0; }
    __syncthreads();
    int e0 = c*CHUNK, e1 = min(E, e0+CHUNK);
    for (int e = e0+t; e < e1; e += 256){
        int s = ei[e], d = ei[E+e];
        atomicAdd(&hd[d>>shift], 1);
        atomicAdd(&hs[s>>shift], 1);
    }
    __syncthreads();
    for (int i=t;i<B;i+=256){
        cnt[(size_t)i*C + c]     = hd[i];
        cnt[(size_t)(B+i)*C + c] = hs[i];
    }
}

// ============ single-pass exclusive scan (decoupled lookback) ============
#define SEPT 16
#define STILE 4096
__global__ __launch_bounds__(256) void k_scan(int* __restrict__ a, int M,
        unsigned long long* __restrict__ state, int* __restrict__ ticket){
    __shared__ int bid_s, exc_s;
    __shared__ int s[256];
    int t = threadIdx.x;
    if (t == 0) bid_s = atomicAdd(ticket, 1);
    __syncthreads();
    int bid = bid_s;
    int base = bid*STILE + t*SEPT;
    int v[SEPT]; int sum = 0;
    #pragma unroll
    for (int i=0;i<SEPT;i++){ int idx=base+i; int x=(idx<M)?a[idx]:0; v[i]=sum; sum+=x; }
    s[t]=sum; __syncthreads();
    for (int o=1;o<256;o<<=1){ int x=(t>=o)?s[t-o]:0; __syncthreads(); s[t]+=x; __syncthreads(); }
    int tot = s[255];
    int te = s[t]-sum;
    if (t == 0){
        unsigned long long pub = ((bid==0) ? (2ull<<62) : (1ull<<62)) | (unsigned long long)(unsigned)tot;
        __hip_atomic_store(&state[bid], pub, __ATOMIC_RELEASE, __HIP_MEMORY_SCOPE_AGENT);
        int exc = 0;
        if (bid > 0){
            int p = bid-1;
            while (true){
                unsigned long long st = __hip_atomic_load(&state[p], __ATOMIC_ACQUIRE, __HIP_MEMORY_SCOPE_AGENT);
                unsigned long long fl = st >> 62;
                if (fl == 2ull){ exc += (int)(unsigned)st; break; }
                if (fl == 1ull){ exc += (int)(unsigned)st; p--; }
            }
            __hip_atomic_store(&state[bid],
                (2ull<<62) | (unsigned long long)(unsigned)(exc + tot),
                __ATOMIC_RELEASE, __HIP_MEMORY_SCOPE_AGENT);
        }
        exc_s = exc;
    }
    __syncthreads();
    int exc = exc_s;
    #pragma unroll
    for (int i=0;i<SEPT;i++){ int idx=base+i; if (idx<M) a[idx]=exc+te+v[i]; }
}

// ============ scatter edges into bucket-grouped temps ============
__global__ __launch_bounds__(256) void k_scatter(const int* __restrict__ ei, int E,
        int B, int C, int shift, const int* __restrict__ scan,
        uint32_t* __restrict__ tempD, uint16_t* __restrict__ tempS){
    __shared__ int cd[MAXB], cs[MAXB];
    int t = threadIdx.x, c = blockIdx.x;
    for (int i=t;i<B;i+=256){
        cd[i] = scan[(size_t)i*C + c];
        cs[i] = scan[(size_t)(B+i)*C + c] - E;
    }
    __syncthreads();
    int e0 = c*CHUNK, e1 = min(E, e0+CHUNK);
    int lmask = (1<<shift) - 1;
    for (int e = e0+t; e < e1; e += 256){
        int s = ei[e], d = ei[E+e];
        int p = atomicAdd(&cd[d>>shift], 1);
        tempD[p] = ((uint32_t)(d & lmask) << 20) | (uint32_t)s;
        int q = atomicAdd(&cs[s>>shift], 1);
        tempS[q] = (uint16_t)s;
    }
}

// ============ per-bucket: row_off + csr (dst) and deg_out (src) ============
__global__ __launch_bounds__(256) void k_build2(const uint32_t* __restrict__ tempD,
        const uint16_t* __restrict__ tempS, const int* __restrict__ scan,
        int B, int C, int shift, int E, int N,
        int* __restrict__ row_off, int* __restrict__ csr, int* __restrict__ deg_out){
    __shared__ int cnt[MAXB];
    __shared__ int offl[MAXB];
    int b = blockIdx.x, t = threadIdx.x;
    int range = 1<<shift, nb0 = b<<shift;
    int seg0 = scan[(size_t)b*C];
    int seg1 = (b+1<B) ? scan[(size_t)(b+1)*C] : E;
    for (int i=t;i<range;i+=256) cnt[i]=0;
    __syncthreads();
    for (int i=seg0+t; i<seg1; i+=256)
        atomicAdd(&cnt[tempD[i]>>20], 1);
    __syncthreads();
    if (t==0){ int run=0; for (int i=0;i<range;i++){ offl[i]=run; run+=cnt[i]; } }
    __syncthreads();
    for (int i=t;i<range;i+=256){
        int node = nb0+i;
        if (node < N) row_off[node] = seg0 + offl[i];
    }
    if (b==B-1 && t==0) row_off[N] = E;
    for (int i=t;i<range;i+=256) cnt[i] = offl[i];
    __syncthreads();
    for (int i=seg0+t; i<seg1; i+=256){
        uint32_t v = tempD[i];
        int p = atomicAdd(&cnt[v>>20], 1);
        csr[seg0 + p] = (int)(v & 0xFFFFFu);
    }
    __syncthreads();
    int sg0 = scan[(size_t)(B+b)*C] - E;
    int sg1 = ((b+1<B) ? scan[(size_t)(B+b+1)*C] : 2*E) - E;
    for (int i=t;i<range;i+=256) cnt[i]=0;
    __syncthreads();
    for (int i=sg0+t; i<sg1; i+=256)
        atomicAdd(&cnt[(int)tempS[i] - nb0], 1);
    __syncthreads();
    for (int i=t;i<range;i+=256){
        int node = nb0+i;
        if (node < N) deg_out[node] = cnt[i];
    }
}

// ============ GEMM (swapped-operand MFMA) -> fp8 output ============
__global__ __launch_bounds__(256) void k_gemm(const void* __restrict__ A,
        const uint16_t* __restrict__ Wf, const int* __restrict__ deg_out,
        uint8_t* __restrict__ out8, int nrows, int amode){
    int t = threadIdx.x;
    int wave = t>>6, lane = t&63, quad = lane>>4, low = lane&15;

    int rowA  = blockIdx.x*64 + wave*16 + low;
    int rowAc = min(rowA, nrows-1);

    bf16x8 ah[4];
    if (amode){
        const uint16_t* arow = (const uint16_t*)A + (size_t)rowAc*FD;
        #pragma unroll
        for (int kk=0;kk<4;kk++)
            ah[kk] = *(const bf16x8*)(arow + kk*32 + quad*8);
    } else {
        const float* arow = (const float*)A + (size_t)rowAc*FD;
        #pragma unroll
        for (int kk=0;kk<4;kk++){
            f32x4 f0 = *(const f32x4*)(arow + kk*32 + quad*8);
            f32x4 f1 = *(const f32x4*)(arow + kk*32 + quad*8 + 4);
            #pragma unroll
            for (int j=0;j<4;j++) ah[kk][j]   = (short)f2bf(f0[j]);
            #pragma unroll
            for (int j=0;j<4;j++) ah[kk][j+4] = (short)f2bf(f1[j]);
        }
    }

    f32x4 acc[8];
    #pragma unroll
    for (int n=0;n<8;n++) acc[n] = (f32x4){0.f,0.f,0.f,0.f};

    #pragma unroll
    for (int kk=0;kk<4;kk++){
        #pragma unroll
        for (int n=0;n<8;n++){
            bf16x8 bh = *(const bf16x8*)(Wf + ((size_t)((kk*8+n)*64 + lane))*8);
            acc[n] = __builtin_amdgcn_mfma_f32_16x16x32_bf16(bh, ah[kk], acc[n], 0, 0, 0);
        }
    }

    if (rowA < nrows){
        float sc = rsqrtf((float)max(deg_out[rowA], 1));
        uint8_t* orow = out8 + (size_t)rowA*FD;
        #pragma unroll
        for (int n=0;n<8;n++){
            uint32_t pk = pk4fp8(acc[n][0]*sc, acc[n][1]*sc, acc[n][2]*sc, acc[n][3]*sc);
            *(uint32_t*)(orow + n*16 + quad*4) = pk;
        }
    }
}

// ============ SpMM: wave per node, quarter-wave per edge, 8B/lane ============
// Full 128B fp8 row per edge in one pass: 16 lanes x uint2. One 512B load
// instruction covers 4 edges (vs 256B/2 edges before) - half the issue rate.
__global__ __launch_bounds__(256) void k_spmm(const uint8_t* __restrict__ tmp8,
        const int* __restrict__ row_off, const int* __restrict__ csr_src,
        const float* __restrict__ bias, uint16_t* __restrict__ hout, int N){
    int node = blockIdx.x*4 + (threadIdx.x>>6);
    int lane = threadIdx.x & 63;
    int l4 = lane & 15, q = lane >> 4;
    if (node >= N) return;
    int e0 = row_off[node], e1 = row_off[node+1];
    const uint2* tp = (const uint2*)tmp8;      // row = 16 x uint2 (128 B)
    f32x2 a01={0.f,0.f}, a23={0.f,0.f}, a45={0.f,0.f}, a67={0.f,0.f};
    for (int base = e0; base < e1; base += 64){
        int my = 0;
        if (base + lane < e1) my = csr_src[base + lane];
        int cnt = min(64, e1 - base);
        for (int j = 0; j < cnt; j += 16){
            int i0 = j + q, i1 = j + 4 + q, i2 = j + 8 + q, i3 = j + 12 + q;
            int s0 = __shfl(my, min(i0, cnt-1));
            int s1 = __shfl(my, min(i1, cnt-1));
            int s2 = __shfl(my, min(i2, cnt-1));
            int s3 = __shfl(my, min(i3, cnt-1));
            uint2 p0 = tp[(size_t)s0*16 + l4];
            uint2 p1 = tp[(size_t)s1*16 + l4];
            uint2 p2 = tp[(size_t)s2*16 + l4];
            uint2 p3 = tp[(size_t)s3*16 + l4];
            if (i0 < cnt){ a01 += fp8lo2f(p0.x); a23 += fp8hi2f(p0.x);
                           a45 += fp8lo2f(p0.y); a67 += fp8hi2f(p0.y); }
            if (i1 < cnt){ a01 += fp8lo2f(p1.x); a23 += fp8hi2f(p1.x);
                           a45 += fp8lo2f(p1.y); a67 += fp8hi2f(p1.y); }
            if (i2 < cnt){ a01 += fp8lo2f(p2.x); a23 += fp8hi2f(p2.x);
                           a45 += fp8lo2f(p2.y); a67 += fp8hi2f(p2.y); }
            if (i3 < cnt){ a01 += fp8lo2f(p3.x); a23 += fp8hi2f(p3.x);
                           a45 += fp8lo2f(p3.y); a67 += fp8hi2f(p3.y); }
        }
    }
    // reduce across the 4 quarters (lanes sharing l4 hold the same 8 cols)
    a01.x += __shfl_xor(a01.x, 16); a01.x += __shfl_xor(a01.x, 32);
    a01.y += __shfl_xor(a01.y, 16); a01.y += __shfl_xor(a01.y, 32);
    a23.x += __shfl_xor(a23.x, 16); a23.x += __shfl_xor(a23.x, 32);
    a23.y += __shfl_xor(a23.y, 16); a23.y += __shfl_xor(a23.y, 32);
    a45.x += __shfl_xor(a45.x, 16); a45.x += __shfl_xor(a45.x, 32);
    a45.y += __shfl_xor(a45.y, 16); a45.y += __shfl_xor(a45.y, 32);
    a67.x += __shfl_xor(a67.x, 16); a67.x += __shfl_xor(a67.x, 32);
    a67.y += __shfl_xor(a67.y, 16); a67.y += __shfl_xor(a67.y, 32);
    if (q == 0){
        float isq = rsqrtf((float)max(e1 - e0, 1));
        f32x4 b0 = *(const f32x4*)(bias + l4*8);
        f32x4 b1 = *(const f32x4*)(bias + l4*8 + 4);
        float r0 = fmaxf(a01.x*isq + b0[0], 0.f);
        float r1 = fmaxf(a01.y*isq + b0[1], 0.f);
        float r2 = fmaxf(a23.x*isq + b0[2], 0.f);
        float r3 = fmaxf(a23.y*isq + b0[3], 0.f);
        float r4 = fmaxf(a45.x*isq + b1[0], 0.f);
        float r5 = fmaxf(a45.y*isq + b1[1], 0.f);
        float r6 = fmaxf(a67.x*isq + b1[2], 0.f);
        float r7 = fmaxf(a67.y*isq + b1[3], 0.f);
        uint4 o;
        o.x = (uint32_t)f2bf(r0) | ((uint32_t)f2bf(r1) << 16);
        o.y = (uint32_t)f2bf(r2) | ((uint32_t)f2bf(r3) << 16);
        o.z = (uint32_t)f2bf(r4) | ((uint32_t)f2bf(r5) << 16);
        o.w = (uint32_t)f2bf(r6) | ((uint32_t)f2bf(r7) << 16);
        *(uint4*)(hout + (size_t)node*FD + l4*8) = o;
    }
}

// ============ pool: batched loads, run-length accumulate ============
__global__ __launch_bounds__(256) void k_pool(const uint16_t* __restrict__ h,
        const int* __restrict__ n2g, int N, float* __restrict__ pool){
    __shared__ float sacc[NG*FD];
    int t = threadIdx.x;
    for (int i = t; i < NG*FD; i += 256) sacc[i] = 0.f;
    __syncthreads();
    int fp = t & 63;
    int no = t >> 6;
    const uint32_t* hp = (const uint32_t*)h;
    int base = blockIdx.x * 64;
    int gg[16]; uint32_t pv[16];
    #pragma unroll
    for (int i = 0; i < 16; i++){
        int node = base + i*4 + no;
        int nc = min(node, N-1);
        gg[i] = n2g[nc];
        uint32_t v = hp[(size_t)nc*64 + fp];
        pv[i] = (node < N) ? v : 0u;
    }
    float r0 = 0.f, r1 = 0.f; int rg = gg[0];
    #pragma unroll
    for (int i = 0; i < 16; i++){
        if (gg[i] != rg){
            atomicAdd(&sacc[rg*FD + fp*2],     r0);
            atomicAdd(&sacc[rg*FD + fp*2 + 1], r1);
            r0 = r1 = 0.f; rg = gg[i];
        }
        r0 += bf2f((uint16_t)(pv[i] & 0xffff));
        r1 += bf2f((uint16_t)(pv[i] >> 16));
    }
    atomicAdd(&sacc[rg*FD + fp*2],     r0);
    atomicAdd(&sacc[rg*FD + fp*2 + 1], r1);
    __syncthreads();
    for (int i = t; i < NG*FD; i += 256){
        float v = sacc[i];
        if (v != 0.f) atomicAdd(&pool[i], v);
    }
}

// ============ mean, linear, softmax -> 80 f32 ============
__global__ __launch_bounds__(128) void k_final(const float* __restrict__ pool,
        const int* __restrict__ n2g, int N, const float* __restrict__ Wl,
        const float* __restrict__ bl, float* __restrict__ out){
    __shared__ int ub[NG+1];
    __shared__ float logits[NG][NC];
    int t = threadIdx.x;
    if (t <= NG){
        int lo = 0, hi = N;
        while (lo < hi){ int mid = (lo+hi)>>1; if (n2g[mid] < t) lo = mid+1; else hi = mid; }
        ub[t] = lo;
    }
    __syncthreads();
    if (t < NG*NC){
        int g = t/NC, c = t%NC;
        float cnt = (float)max(ub[g+1]-ub[g], 1);
        float inv = 1.f/cnt;
        float acc = bl[c];
        for (int d=0; d<FD; d++)
            acc += pool[g*FD+d]*inv * Wl[d*NC+c];
        logits[g][c] = acc;
    }
    __syncthreads();
    if (t < NG*NC){
        int g = t/NC, c = t%NC;
        float m = -1e30f;
        for (int i=0;i<NC;i++) m = fmaxf(m, logits[g][i]);
        float ssum = 0.f;
        for (int i=0;i<NC;i++) ssum += expf(logits[g][i]-m);
        out[t] = expf(logits[g][c]-m)/ssum;
    }
}

extern "C" void kernel_launch(void* const* d_in, const int* in_sizes, int n_in,
                              void* d_out, int out_size, void* d_ws, size_t ws_size,
                              hipStream_t stream) {
    const float* x   = (const float*)d_in[0];
    const int*   ei  = (const int*)d_in[1];
    const int*   n2g = (const int*)d_in[2];
    const float* W1  = (const float*)d_in[3];
    const float* b1  = (const float*)d_in[4];
    const float* W2  = (const float*)d_in[5];
    const float* b2  = (const float*)d_in[6];
    const float* Wl  = (const float*)d_in[7];
    const float* bl  = (const float*)d_in[8];
    float* outp = (float*)d_out;

    int N = in_sizes[2];
    int E = in_sizes[1] / 2;

    int shift = 6;
    while ((((N + (1<<shift) - 1) >> shift) > MAXB) && shift < 10) shift++;
    int B = (N + (1<<shift) - 1) >> shift;
    int C = (E + CHUNK - 1) / CHUNK;
    int M = 2*B*C;
    int nscan = (M + STILE - 1) / STILE;   // <= 1024 (state array)

    char* w = (char*)d_ws;
    size_t off = 0;
    auto alloc = [&](size_t bytes)->char*{ char* p = w + off; off += (bytes + 255) & ~(size_t)255; return p; };
    float*    pool    = (float*)alloc((size_t)NG*FD*4);
    unsigned long long* state = (unsigned long long*)alloc(1024*8);
    int*      counters= (int*)alloc(8*4);       // [0]=scan ticket
    int*      deg_out = (int*)alloc((size_t)N*4);
    int*      row_off = (int*)alloc((size_t)(N+1)*4);
    int*      csr     = (int*)alloc((size_t)E*4);
    uint16_t* Wf1     = (uint16_t*)alloc(16384*2);
    uint16_t* Wf2     = (uint16_t*)alloc(16384*2);
    uint8_t*  tmp8    = (uint8_t*)alloc((size_t)N*FD);
    uint16_t* hb      = (uint16_t*)alloc((size_t)N*FD*2);
    (void)ws_size;
    // aliases (live only during CSR build, before tmp8/hb are written)
    uint32_t* tempD = (uint32_t*)tmp8;                      // E*4 <= N*FD
    uint16_t* tempS = (uint16_t*)(tmp8 + (size_t)E*4);      // +E*2
    int* cnt = (int*)hb;                                    // M*4 <= N*FD*2

    k_prep   <<<128 + C, 256, 0, stream>>>(W1, W2, Wf1, Wf2, ei, E, B, C, shift,
                                           cnt, pool, state, counters);
    k_scan   <<<nscan, 256, 0, stream>>>(cnt, M, state, &counters[0]);
    k_scatter<<<C, 256, 0, stream>>>(ei, E, B, C, shift, cnt, tempD, tempS);
    k_build2 <<<B, 256, 0, stream>>>(tempD, tempS, cnt, B, C, shift, E, N, row_off, csr, deg_out);

    int gb = (N + 63)/64;
    int sb = (N + 3)/4;
    int pb = (N + 63)/64;
    k_gemm  <<<gb, 256, 0, stream>>>(x,  Wf1, deg_out, tmp8, N, 0);
    k_spmm  <<<sb, 256, 0, stream>>>(tmp8, row_off, csr, b1, hb, N);
    k_gemm  <<<gb, 256, 0, stream>>>(hb, Wf2, deg_out, tmp8, N, 1);
    k_spmm  <<<sb, 256, 0, stream>>>(tmp8, row_off, csr, b2, hb, N);
    k_pool  <<<pb, 256, 0, stream>>>(hb, n2g, N, pool);
    k_final <<<1,  128, 0, stream>>>(pool, n2g, N, Wl, bl, outp);
}

// Round 14
// 223.319 us; speedup vs baseline: 6.9240x; 1.0359x over previous
//
#include <hip/hip_runtime.h>
#include <stdint.h>

#define FD 128   // feature dim
#define NG 8     // graphs
#define NC 10    // classes
#define MAXB 1024           // max buckets
#define CHUNK 4096          // edges per counting chunk

typedef __attribute__((ext_vector_type(8))) short bf16x8;
typedef __attribute__((ext_vector_type(4))) float f32x4;
typedef __attribute__((ext_vector_type(2))) float f32x2;

__device__ __forceinline__ float bf2f(uint16_t u){
    union { uint32_t i; float f; } v; v.i = ((uint32_t)u) << 16; return v.f;
}
__device__ __forceinline__ uint16_t f2bf(float f){
    union { float f; uint32_t i; } v; v.f = f;
    uint32_t r = v.i + 0x7fff + ((v.i >> 16) & 1);
    return (uint16_t)(r >> 16);
}

// ---- fp8 e4m3 conversions (HW path with manual fallback) ----
#if __has_builtin(__builtin_amdgcn_cvt_pk_f32_fp8) && __has_builtin(__builtin_amdgcn_cvt_pk_fp8_f32)
__device__ __forceinline__ f32x2 fp8lo2f(uint32_t p){
    return __builtin_amdgcn_cvt_pk_f32_fp8((int)p, false);
}
__device__ __forceinline__ f32x2 fp8hi2f(uint32_t p){
    return __builtin_amdgcn_cvt_pk_f32_fp8((int)p, true);
}
__device__ __forceinline__ uint32_t pk4fp8(float a, float b, float c, float d){
    int u = 0;
    u = __builtin_amdgcn_cvt_pk_fp8_f32(a, b, u, false);
    u = __builtin_amdgcn_cvt_pk_fp8_f32(c, d, u, true);
    return (uint32_t)u;
}
#else
__device__ __forceinline__ float fp8tof(uint32_t b){
    union { uint32_t i; float f; } v;
    v.i = ((b & 0x7f) << 20) | ((b & 0x80) << 24);
    return v.f * 0x1p120f;
}
__device__ __forceinline__ f32x2 fp8lo2f(uint32_t p){
    return (f32x2){fp8tof(p & 0xff), fp8tof((p >> 8) & 0xff)};
}
__device__ __forceinline__ f32x2 fp8hi2f(uint32_t p){
    return (f32x2){fp8tof((p >> 16) & 0xff), fp8tof((p >> 24) & 0xff)};
}
__device__ __forceinline__ uint32_t f2fp8(float f){
    union { float f; uint32_t i; } v; v.f = f;
    uint32_t s = (v.i >> 24) & 0x80;
    float a = fabsf(f);
    if (a < 0x1p-10f) return s;
    if (a > 448.f) return s | 0x7e;
    v.f = a;
    uint32_t r = v.i + 0x7ffff + ((v.i >> 20) & 1);
    int e = (int)(r >> 23) - 127 + 7;
    uint32_t m = (r >> 20) & 7;
    if (e <= 0){
        uint32_t q = (uint32_t)(a * 512.f + 0.5f);
        return s | (q > 7 ? 8 : q);
    }
    if (e > 15) return s | 0x7e;
    return s | ((uint32_t)e << 3) | m;
}
__device__ __forceinline__ uint32_t pk4fp8(float a, float b, float c, float d){
    return (uint32_t)f2fp8(a) | ((uint32_t)f2fp8(b)<<8) |
           ((uint32_t)f2fp8(c)<<16) | ((uint32_t)f2fp8(d)<<24);
}
#endif

// ============ Fused: prep_w + per-chunk histograms + zero-init ============
__global__ __launch_bounds__(256) void k_prep(const float* __restrict__ W1,
        const float* __restrict__ W2, uint16_t* Wf1, uint16_t* Wf2,
        const int* __restrict__ ei, int E, int B, int C, int shift,
        int* __restrict__ cnt, float* __restrict__ pool,
        unsigned long long* __restrict__ state, int* __restrict__ counters){
    int t = threadIdx.x;
    if (blockIdx.x < 128){
        int id = blockIdx.x*256 + t;
        int w = id >> 14;
        int r = id & 16383;
        int j = r & 7, frag = r >> 3;
        int lane = frag & 63, t2 = frag >> 6;
        int n = t2 & 7, kk = t2 >> 3;
        int k = kk*32 + (lane>>4)*8 + j;
        int col = n*16 + (lane&15);
        float v = (w ? W2 : W1)[k*128 + col];
        (w ? Wf2 : Wf1)[r] = f2bf(v);
        if (blockIdx.x == 0){
            for (int i = t; i < NG*FD; i += 256) pool[i] = 0.f;
            for (int i = t; i < 1024; i += 256) state[i] = 0ull;
            if (t < 8) counters[t] = 0;
        }
        return;
    }
    __shared__ int hd[MAXB], hs[MAXB];
    int c = blockIdx.x - 128;
    for (int i=t;i<B;i+=256){ hd[i]=0; hs[i]=0; }
    __syncthreads();
    int e0 = c*CHUNK, e1 = min(E, e0+CHUNK);
    for (int e = e0+t; e < e1; e += 256){
        int s = ei[e], d = ei[E+e];
        atomicAdd(&hd[d>>shift], 1);
        atomicAdd(&hs[s>>shift], 1);
    }
    __syncthreads();
    for (int i=t;i<B;i+=256){
        cnt[(size_t)i*C + c]     = hd[i];
        cnt[(size_t)(B+i)*C + c] = hs[i];
    }
}

// ============ single-pass exclusive scan (decoupled lookback) ============
#define SEPT 16
#define STILE 4096
__global__ __launch_bounds__(256) void k_scan(int* __restrict__ a, int M,
        unsigned long long* __restrict__ state, int* __restrict__ ticket){
    __shared__ int bid_s, exc_s;
    __shared__ int s[256];
    int t = threadIdx.x;
    if (t == 0) bid_s = atomicAdd(ticket, 1);
    __syncthreads();
    int bid = bid_s;
    int base = bid*STILE + t*SEPT;
    int v[SEPT]; int sum = 0;
    #pragma unroll
    for (int i=0;i<SEPT;i++){ int idx=base+i; int x=(idx<M)?a[idx]:0; v[i]=sum; sum+=x; }
    s[t]=sum; __syncthreads();
    for (int o=1;o<256;o<<=1){ int x=(t>=o)?s[t-o]:0; __syncthreads(); s[t]+=x; __syncthreads(); }
    int tot = s[255];
    int te = s[t]-sum;
    if (t == 0){
        unsigned long long pub = ((bid==0) ? (2ull<<62) : (1ull<<62)) | (unsigned long long)(unsigned)tot;
        __hip_atomic_store(&state[bid], pub, __ATOMIC_RELEASE, __HIP_MEMORY_SCOPE_AGENT);
        int exc = 0;
        if (bid > 0){
            int p = bid-1;
            while (true){
                unsigned long long st = __hip_atomic_load(&state[p], __ATOMIC_ACQUIRE, __HIP_MEMORY_SCOPE_AGENT);
                unsigned long long fl = st >> 62;
                if (fl == 2ull){ exc += (int)(unsigned)st; break; }
                if (fl == 1ull){ exc += (int)(unsigned)st; p--; }
            }
            __hip_atomic_store(&state[bid],
                (2ull<<62) | (unsigned long long)(unsigned)(exc + tot),
                __ATOMIC_RELEASE, __HIP_MEMORY_SCOPE_AGENT);
        }
        exc_s = exc;
    }
    __syncthreads();
    int exc = exc_s;
    #pragma unroll
    for (int i=0;i<SEPT;i++){ int idx=base+i; if (idx<M) a[idx]=exc+te+v[i]; }
}

// ============ scatter edges into bucket-grouped temps ============
__global__ __launch_bounds__(256) void k_scatter(const int* __restrict__ ei, int E,
        int B, int C, int shift, const int* __restrict__ scan,
        uint32_t* __restrict__ tempD, uint16_t* __restrict__ tempS){
    __shared__ int cd[MAXB], cs[MAXB];
    int t = threadIdx.x, c = blockIdx.x;
    for (int i=t;i<B;i+=256){
        cd[i] = scan[(size_t)i*C + c];
        cs[i] = scan[(size_t)(B+i)*C + c] - E;
    }
    __syncthreads();
    int e0 = c*CHUNK, e1 = min(E, e0+CHUNK);
    int lmask = (1<<shift) - 1;
    for (int e = e0+t; e < e1; e += 256){
        int s = ei[e], d = ei[E+e];
        int p = atomicAdd(&cd[d>>shift], 1);
        tempD[p] = ((uint32_t)(d & lmask) << 20) | (uint32_t)s;
        int q = atomicAdd(&cs[s>>shift], 1);
        tempS[q] = (uint16_t)s;
    }
}

// ============ per-bucket: row_off + csr (dst) and deg_out (src) ============
__global__ __launch_bounds__(256) void k_build2(const uint32_t* __restrict__ tempD,
        const uint16_t* __restrict__ tempS, const int* __restrict__ scan,
        int B, int C, int shift, int E, int N,
        int* __restrict__ row_off, int* __restrict__ csr, int* __restrict__ deg_out){
    __shared__ int cnt[MAXB];
    __shared__ int offl[MAXB];
    int b = blockIdx.x, t = threadIdx.x;
    int range = 1<<shift, nb0 = b<<shift;
    int seg0 = scan[(size_t)b*C];
    int seg1 = (b+1<B) ? scan[(size_t)(b+1)*C] : E;
    for (int i=t;i<range;i+=256) cnt[i]=0;
    __syncthreads();
    for (int i=seg0+t; i<seg1; i+=256)
        atomicAdd(&cnt[tempD[i]>>20], 1);
    __syncthreads();
    if (t==0){ int run=0; for (int i=0;i<range;i++){ offl[i]=run; run+=cnt[i]; } }
    __syncthreads();
    for (int i=t;i<range;i+=256){
        int node = nb0+i;
        if (node < N) row_off[node] = seg0 + offl[i];
    }
    if (b==B-1 && t==0) row_off[N] = E;
    for (int i=t;i<range;i+=256) cnt[i] = offl[i];
    __syncthreads();
    for (int i=seg0+t; i<seg1; i+=256){
        uint32_t v = tempD[i];
        int p = atomicAdd(&cnt[v>>20], 1);
        csr[seg0 + p] = (int)(v & 0xFFFFFu);
    }
    __syncthreads();
    int sg0 = scan[(size_t)(B+b)*C] - E;
    int sg1 = ((b+1<B) ? scan[(size_t)(B+b+1)*C] : 2*E) - E;
    for (int i=t;i<range;i+=256) cnt[i]=0;
    __syncthreads();
    for (int i=sg0+t; i<sg1; i+=256)
        atomicAdd(&cnt[(int)tempS[i] - nb0], 1);
    __syncthreads();
    for (int i=t;i<range;i+=256){
        int node = nb0+i;
        if (node < N) deg_out[node] = cnt[i];
    }
}

// ============ GEMM (swapped-operand MFMA) -> fp8 output ============
__global__ __launch_bounds__(256) void k_gemm(const void* __restrict__ A,
        const uint16_t* __restrict__ Wf, const int* __restrict__ deg_out,
        uint8_t* __restrict__ out8, int nrows, int amode){
    int t = threadIdx.x;
    int wave = t>>6, lane = t&63, quad = lane>>4, low = lane&15;

    int rowA  = blockIdx.x*64 + wave*16 + low;
    int rowAc = min(rowA, nrows-1);

    bf16x8 ah[4];
    if (amode){
        const uint16_t* arow = (const uint16_t*)A + (size_t)rowAc*FD;
        #pragma unroll
        for (int kk=0;kk<4;kk++)
            ah[kk] = *(const bf16x8*)(arow + kk*32 + quad*8);
    } else {
        const float* arow = (const float*)A + (size_t)rowAc*FD;
        #pragma unroll
        for (int kk=0;kk<4;kk++){
            f32x4 f0 = *(const f32x4*)(arow + kk*32 + quad*8);
            f32x4 f1 = *(const f32x4*)(arow + kk*32 + quad*8 + 4);
            #pragma unroll
            for (int j=0;j<4;j++) ah[kk][j]   = (short)f2bf(f0[j]);
            #pragma unroll
            for (int j=0;j<4;j++) ah[kk][j+4] = (short)f2bf(f1[j]);
        }
    }

    f32x4 acc[8];
    #pragma unroll
    for (int n=0;n<8;n++) acc[n] = (f32x4){0.f,0.f,0.f,0.f};

    #pragma unroll
    for (int kk=0;kk<4;kk++){
        #pragma unroll
        for (int n=0;n<8;n++){
            bf16x8 bh = *(const bf16x8*)(Wf + ((size_t)((kk*8+n)*64 + lane))*8);
            acc[n] = __builtin_amdgcn_mfma_f32_16x16x32_bf16(bh, ah[kk], acc[n], 0, 0, 0);
        }
    }

    if (rowA < nrows){
        float sc = rsqrtf((float)max(deg_out[rowA], 1));
        uint8_t* orow = out8 + (size_t)rowA*FD;
        #pragma unroll
        for (int n=0;n<8;n++){
            uint32_t pk = pk4fp8(acc[n][0]*sc, acc[n][1]*sc, acc[n][2]*sc, acc[n][3]*sc);
            *(uint32_t*)(orow + n*16 + quad*4) = pk;
        }
    }
}

// ============ SpMM: QUARTER-WAVE PER NODE, 8B/lane ============
// 16 lanes cover one 128B fp8 row; each quarter owns its own node (identical
// control flow within quarter; shfl stays inside the quarter). 4 edges
// batched -> 16 gathers in flight per wave; no cross-lane reduction.
__global__ __launch_bounds__(256) void k_spmm(const uint8_t* __restrict__ tmp8,
        const int* __restrict__ row_off, const int* __restrict__ csr_src,
        const float* __restrict__ bias, uint16_t* __restrict__ hout, int N){
    int tid = threadIdx.x;
    int node = blockIdx.x*16 + (tid>>4);
    int l  = tid & 15;           // lane within quarter
    int qb = (tid & 63) & 48;    // quarter base within the wave
    if (node >= N) return;
    int e0 = row_off[node], e1 = row_off[node+1];
    const uint2* tp = (const uint2*)tmp8;      // row = 16 x uint2 (128 B)
    f32x2 a01={0.f,0.f}, a23={0.f,0.f}, a45={0.f,0.f}, a67={0.f,0.f};
    for (int base = e0; base < e1; base += 16){
        int my = 0;
        if (base + l < e1) my = csr_src[base + l];
        int cnt = min(16, e1 - base);
        for (int j = 0; j < cnt; j += 4){
            int i1 = j+1, i2 = j+2, i3 = j+3;
            int s0 = __shfl(my, qb + j);
            int s1 = __shfl(my, qb + min(i1, cnt-1));
            int s2 = __shfl(my, qb + min(i2, cnt-1));
            int s3 = __shfl(my, qb + min(i3, cnt-1));
            uint2 p0 = tp[(size_t)s0*16 + l];
            uint2 p1 = tp[(size_t)s1*16 + l];
            uint2 p2 = tp[(size_t)s2*16 + l];
            uint2 p3 = tp[(size_t)s3*16 + l];
            a01 += fp8lo2f(p0.x); a23 += fp8hi2f(p0.x);
            a45 += fp8lo2f(p0.y); a67 += fp8hi2f(p0.y);
            if (i1 < cnt){ a01 += fp8lo2f(p1.x); a23 += fp8hi2f(p1.x);
                           a45 += fp8lo2f(p1.y); a67 += fp8hi2f(p1.y); }
            if (i2 < cnt){ a01 += fp8lo2f(p2.x); a23 += fp8hi2f(p2.x);
                           a45 += fp8lo2f(p2.y); a67 += fp8hi2f(p2.y); }
            if (i3 < cnt){ a01 += fp8lo2f(p3.x); a23 += fp8hi2f(p3.x);
                           a45 += fp8lo2f(p3.y); a67 += fp8hi2f(p3.y); }
        }
    }
    float isq = rsqrtf((float)max(e1 - e0, 1));
    f32x4 b0 = *(const f32x4*)(bias + l*8);
    f32x4 b1 = *(const f32x4*)(bias + l*8 + 4);
    float r0 = fmaxf(a01.x*isq + b0[0], 0.f);
    float r1 = fmaxf(a01.y*isq + b0[1], 0.f);
    float r2 = fmaxf(a23.x*isq + b0[2], 0.f);
    float r3 = fmaxf(a23.y*isq + b0[3], 0.f);
    float r4 = fmaxf(a45.x*isq + b1[0], 0.f);
    float r5 = fmaxf(a45.y*isq + b1[1], 0.f);
    float r6 = fmaxf(a67.x*isq + b1[2], 0.f);
    float r7 = fmaxf(a67.y*isq + b1[3], 0.f);
    uint4 o;
    o.x = (uint32_t)f2bf(r0) | ((uint32_t)f2bf(r1) << 16);
    o.y = (uint32_t)f2bf(r2) | ((uint32_t)f2bf(r3) << 16);
    o.z = (uint32_t)f2bf(r4) | ((uint32_t)f2bf(r5) << 16);
    o.w = (uint32_t)f2bf(r6) | ((uint32_t)f2bf(r7) << 16);
    *(uint4*)(hout + (size_t)node*FD + l*8) = o;
}

// ============ pool: batched loads, run-length accumulate ============
__global__ __launch_bounds__(256) void k_pool(const uint16_t* __restrict__ h,
        const int* __restrict__ n2g, int N, float* __restrict__ pool){
    __shared__ float sacc[NG*FD];
    int t = threadIdx.x;
    for (int i = t; i < NG*FD; i += 256) sacc[i] = 0.f;
    __syncthreads();
    int fp = t & 63;
    int no = t >> 6;
    const uint32_t* hp = (const uint32_t*)h;
    int base = blockIdx.x * 64;
    int gg[16]; uint32_t pv[16];
    #pragma unroll
    for (int i = 0; i < 16; i++){
        int node = base + i*4 + no;
        int nc = min(node, N-1);
        gg[i] = n2g[nc];
        uint32_t v = hp[(size_t)nc*64 + fp];
        pv[i] = (node < N) ? v : 0u;
    }
    float r0 = 0.f, r1 = 0.f; int rg = gg[0];
    #pragma unroll
    for (int i = 0; i < 16; i++){
        if (gg[i] != rg){
            atomicAdd(&sacc[rg*FD + fp*2],     r0);
            atomicAdd(&sacc[rg*FD + fp*2 + 1], r1);
            r0 = r1 = 0.f; rg = gg[i];
        }
        r0 += bf2f((uint16_t)(pv[i] & 0xffff));
        r1 += bf2f((uint16_t)(pv[i] >> 16));
    }
    atomicAdd(&sacc[rg*FD + fp*2],     r0);
    atomicAdd(&sacc[rg*FD + fp*2 + 1], r1);
    __syncthreads();
    for (int i = t; i < NG*FD; i += 256){
        float v = sacc[i];
        if (v != 0.f) atomicAdd(&pool[i], v);
    }
}

// ============ mean, linear, softmax -> 80 f32 ============
__global__ __launch_bounds__(128) void k_final(const float* __restrict__ pool,
        const int* __restrict__ n2g, int N, const float* __restrict__ Wl,
        const float* __restrict__ bl, float* __restrict__ out){
    __shared__ int ub[NG+1];
    __shared__ float logits[NG][NC];
    int t = threadIdx.x;
    if (t <= NG){
        int lo = 0, hi = N;
        while (lo < hi){ int mid = (lo+hi)>>1; if (n2g[mid] < t) lo = mid+1; else hi = mid; }
        ub[t] = lo;
    }
    __syncthreads();
    if (t < NG*NC){
        int g = t/NC, c = t%NC;
        float cnt = (float)max(ub[g+1]-ub[g], 1);
        float inv = 1.f/cnt;
        float acc = bl[c];
        for (int d=0; d<FD; d++)
            acc += pool[g*FD+d]*inv * Wl[d*NC+c];
        logits[g][c] = acc;
    }
    __syncthreads();
    if (t < NG*NC){
        int g = t/NC, c = t%NC;
        float m = -1e30f;
        for (int i=0;i<NC;i++) m = fmaxf(m, logits[g][i]);
        float ssum = 0.f;
        for (int i=0;i<NC;i++) ssum += expf(logits[g][i]-m);
        out[t] = expf(logits[g][c]-m)/ssum;
    }
}

extern "C" void kernel_launch(void* const* d_in, const int* in_sizes, int n_in,
                              void* d_out, int out_size, void* d_ws, size_t ws_size,
                              hipStream_t stream) {
    const float* x   = (const float*)d_in[0];
    const int*   ei  = (const int*)d_in[1];
    const int*   n2g = (const int*)d_in[2];
    const float* W1  = (const float*)d_in[3];
    const float* b1  = (const float*)d_in[4];
    const float* W2  = (const float*)d_in[5];
    const float* b2  = (const float*)d_in[6];
    const float* Wl  = (const float*)d_in[7];
    const float* bl  = (const float*)d_in[8];
    float* outp = (float*)d_out;

    int N = in_sizes[2];
    int E = in_sizes[1] / 2;

    int shift = 6;
    while ((((N + (1<<shift) - 1) >> shift) > MAXB) && shift < 10) shift++;
    int B = (N + (1<<shift) - 1) >> shift;
    int C = (E + CHUNK - 1) / CHUNK;
    int M = 2*B*C;
    int nscan = (M + STILE - 1) / STILE;   // <= 1024 (state array)

    char* w = (char*)d_ws;
    size_t off = 0;
    auto alloc = [&](size_t bytes)->char*{ char* p = w + off; off += (bytes + 255) & ~(size_t)255; return p; };
    float*    pool    = (float*)alloc((size_t)NG*FD*4);
    unsigned long long* state = (unsigned long long*)alloc(1024*8);
    int*      counters= (int*)alloc(8*4);       // [0]=scan ticket
    int*      deg_out = (int*)alloc((size_t)N*4);
    int*      row_off = (int*)alloc((size_t)(N+1)*4);
    int*      csr     = (int*)alloc((size_t)E*4);
    uint16_t* Wf1     = (uint16_t*)alloc(16384*2);
    uint16_t* Wf2     = (uint16_t*)alloc(16384*2);
    uint8_t*  tmp8    = (uint8_t*)alloc((size_t)N*FD);
    uint16_t* hb      = (uint16_t*)alloc((size_t)N*FD*2);
    (void)ws_size;
    // aliases (live only during CSR build, before tmp8/hb are written)
    uint32_t* tempD = (uint32_t*)tmp8;                      // E*4 <= N*FD
    uint16_t* tempS = (uint16_t*)(tmp8 + (size_t)E*4);      // +E*2
    int* cnt = (int*)hb;                                    // M*4 <= N*FD*2

    k_prep   <<<128 + C, 256, 0, stream>>>(W1, W2, Wf1, Wf2, ei, E, B, C, shift,
                                           cnt, pool, state, counters);
    k_scan   <<<nscan, 256, 0, stream>>>(cnt, M, state, &counters[0]);
    k_scatter<<<C, 256, 0, stream>>>(ei, E, B, C, shift, cnt, tempD, tempS);
    k_build2 <<<B, 256, 0, stream>>>(tempD, tempS, cnt, B, C, shift, E, N, row_off, csr, deg_out);

    int gb = (N + 63)/64;
    int sb = (N + 15)/16;
    int pb = (N + 63)/64;
    k_gemm  <<<gb, 256, 0, stream>>>(x,  Wf1, deg_out, tmp8, N, 0);
    k_spmm  <<<sb, 256, 0, stream>>>(tmp8, row_off, csr, b1, hb, N);
    k_gemm  <<<gb, 256, 0, stream>>>(hb, Wf2, deg_out, tmp8, N, 1);
    k_spmm  <<<sb, 256, 0, stream>>>(tmp8, row_off, csr, b2, hb, N);
    k_pool  <<<pb, 256, 0, stream>>>(hb, n2g, N, pool);
    k_final <<<1,  128, 0, stream>>>(pool, n2g, N, Wl, bl, outp);
}

// Round 15
// 221.119 us; speedup vs baseline: 6.9929x; 1.0099x over previous
//
#include <hip/hip_runtime.h>
#include <stdint.h>

#define FD 128   // feature dim
#define NG 8     // graphs
#define NC 10    // classes
#define MAXB 1024           // max buckets
#define CHUNK 4096          // edges per counting chunk

typedef __attribute__((ext_vector_type(8))) short bf16x8;
typedef __attribute__((ext_vector_type(4))) float f32x4;
typedef __attribute__((ext_vector_type(2))) float f32x2;

__device__ __forceinline__ float bf2f(uint16_t u){
    union { uint32_t i; float f; } v; v.i = ((uint32_t)u) << 16; return v.f;
}
__device__ __forceinline__ uint16_t f2bf(float f){
    union { float f; uint32_t i; } v; v.f = f;
    uint32_t r = v.i + 0x7fff + ((v.i >> 16) & 1);
    return (uint16_t)(r >> 16);
}

// ---- fp8 e4m3 conversions (HW path with manual fallback) ----
#if __has_builtin(__builtin_amdgcn_cvt_pk_f32_fp8) && __has_builtin(__builtin_amdgcn_cvt_pk_fp8_f32)
__device__ __forceinline__ f32x2 fp8lo2f(uint32_t p){
    return __builtin_amdgcn_cvt_pk_f32_fp8((int)p, false);
}
__device__ __forceinline__ f32x2 fp8hi2f(uint32_t p){
    return __builtin_amdgcn_cvt_pk_f32_fp8((int)p, true);
}
__device__ __forceinline__ uint32_t pk4fp8(float a, float b, float c, float d){
    int u = 0;
    u = __builtin_amdgcn_cvt_pk_fp8_f32(a, b, u, false);
    u = __builtin_amdgcn_cvt_pk_fp8_f32(c, d, u, true);
    return (uint32_t)u;
}
#else
__device__ __forceinline__ float fp8tof(uint32_t b){
    union { uint32_t i; float f; } v;
    v.i = ((b & 0x7f) << 20) | ((b & 0x80) << 24);
    return v.f * 0x1p120f;
}
__device__ __forceinline__ f32x2 fp8lo2f(uint32_t p){
    return (f32x2){fp8tof(p & 0xff), fp8tof((p >> 8) & 0xff)};
}
__device__ __forceinline__ f32x2 fp8hi2f(uint32_t p){
    return (f32x2){fp8tof((p >> 16) & 0xff), fp8tof((p >> 24) & 0xff)};
}
__device__ __forceinline__ uint32_t f2fp8(float f){
    union { float f; uint32_t i; } v; v.f = f;
    uint32_t s = (v.i >> 24) & 0x80;
    float a = fabsf(f);
    if (a < 0x1p-10f) return s;
    if (a > 448.f) return s | 0x7e;
    v.f = a;
    uint32_t r = v.i + 0x7ffff + ((v.i >> 20) & 1);
    int e = (int)(r >> 23) - 127 + 7;
    uint32_t m = (r >> 20) & 7;
    if (e <= 0){
        uint32_t q = (uint32_t)(a * 512.f + 0.5f);
        return s | (q > 7 ? 8 : q);
    }
    if (e > 15) return s | 0x7e;
    return s | ((uint32_t)e << 3) | m;
}
__device__ __forceinline__ uint32_t pk4fp8(float a, float b, float c, float d){
    return (uint32_t)f2fp8(a) | ((uint32_t)f2fp8(b)<<8) |
           ((uint32_t)f2fp8(c)<<16) | ((uint32_t)f2fp8(d)<<24);
}
#endif

// ============ Fused: prep_w + per-chunk histograms + zero-init ============
__global__ __launch_bounds__(256) void k_prep(const float* __restrict__ W1,
        const float* __restrict__ W2, uint16_t* Wf1, uint16_t* Wf2,
        const int* __restrict__ ei, int E, int B, int C, int shift,
        int* __restrict__ cnt, float* __restrict__ pool,
        unsigned long long* __restrict__ state, int* __restrict__ counters){
    int t = threadIdx.x;
    if (blockIdx.x < 128){
        int id = blockIdx.x*256 + t;
        int w = id >> 14;
        int r = id & 16383;
        int j = r & 7, frag = r >> 3;
        int lane = frag & 63, t2 = frag >> 6;
        int n = t2 & 7, kk = t2 >> 3;
        int k = kk*32 + (lane>>4)*8 + j;
        int col = n*16 + (lane&15);
        float v = (w ? W2 : W1)[k*128 + col];
        (w ? Wf2 : Wf1)[r] = f2bf(v);
        if (blockIdx.x == 0){
            for (int i = t; i < NG*FD; i += 256) pool[i] = 0.f;
            for (int i = t; i < 1024; i += 256) state[i] = 0ull;
            if (t < 8) counters[t] = 0;
        }
        return;
    }
    __shared__ int hd[MAXB], hs[MAXB];
    int c = blockIdx.x - 128;
    for (int i=t;i<B;i+=256){ hd[i]=0; hs[i]=0; }
    __syncthreads();
    int e0 = c*CHUNK, e1 = min(E, e0+CHUNK);
    for (int e = e0+t; e < e1; e += 256){
        int s = ei[e], d = ei[E+e];
        atomicAdd(&hd[d>>shift], 1);
        atomicAdd(&hs[s>>shift], 1);
    }
    __syncthreads();
    for (int i=t;i<B;i+=256){
        cnt[(size_t)i*C + c]     = hd[i];
        cnt[(size_t)(B+i)*C + c] = hs[i];
    }
}

// ============ single-pass exclusive scan (decoupled lookback) ============
#define SEPT 16
#define STILE 4096
__global__ __launch_bounds__(256) void k_scan(int* __restrict__ a, int M,
        unsigned long long* __restrict__ state, int* __restrict__ ticket){
    __shared__ int bid_s, exc_s;
    __shared__ int s[256];
    int t = threadIdx.x;
    if (t == 0) bid_s = atomicAdd(ticket, 1);
    __syncthreads();
    int bid = bid_s;
    int base = bid*STILE + t*SEPT;
    int v[SEPT]; int sum = 0;
    #pragma unroll
    for (int i=0;i<SEPT;i++){ int idx=base+i; int x=(idx<M)?a[idx]:0; v[i]=sum; sum+=x; }
    s[t]=sum; __syncthreads();
    for (int o=1;o<256;o<<=1){ int x=(t>=o)?s[t-o]:0; __syncthreads(); s[t]+=x; __syncthreads(); }
    int tot = s[255];
    int te = s[t]-sum;
    if (t == 0){
        unsigned long long pub = ((bid==0) ? (2ull<<62) : (1ull<<62)) | (unsigned long long)(unsigned)tot;
        __hip_atomic_store(&state[bid], pub, __ATOMIC_RELEASE, __HIP_MEMORY_SCOPE_AGENT);
        int exc = 0;
        if (bid > 0){
            int p = bid-1;
            while (true){
                unsigned long long st = __hip_atomic_load(&state[p], __ATOMIC_ACQUIRE, __HIP_MEMORY_SCOPE_AGENT);
                unsigned long long fl = st >> 62;
                if (fl == 2ull){ exc += (int)(unsigned)st; break; }
                if (fl == 1ull){ exc += (int)(unsigned)st; p--; }
            }
            __hip_atomic_store(&state[bid],
                (2ull<<62) | (unsigned long long)(unsigned)(exc + tot),
                __ATOMIC_RELEASE, __HIP_MEMORY_SCOPE_AGENT);
        }
        exc_s = exc;
    }
    __syncthreads();
    int exc = exc_s;
    #pragma unroll
    for (int i=0;i<SEPT;i++){ int idx=base+i; if (idx<M) a[idx]=exc+te+v[i]; }
}

// ============ scatter edges into bucket-grouped temps ============
__global__ __launch_bounds__(256) void k_scatter(const int* __restrict__ ei, int E,
        int B, int C, int shift, const int* __restrict__ scan,
        uint32_t* __restrict__ tempD, uint16_t* __restrict__ tempS){
    __shared__ int cd[MAXB], cs[MAXB];
    int t = threadIdx.x, c = blockIdx.x;
    for (int i=t;i<B;i+=256){
        cd[i] = scan[(size_t)i*C + c];
        cs[i] = scan[(size_t)(B+i)*C + c] - E;
    }
    __syncthreads();
    int e0 = c*CHUNK, e1 = min(E, e0+CHUNK);
    int lmask = (1<<shift) - 1;
    for (int e = e0+t; e < e1; e += 256){
        int s = ei[e], d = ei[E+e];
        int p = atomicAdd(&cd[d>>shift], 1);
        tempD[p] = ((uint32_t)(d & lmask) << 20) | (uint32_t)s;
        int q = atomicAdd(&cs[s>>shift], 1);
        tempS[q] = (uint16_t)s;
    }
}

// ============ per-bucket: row_off + csr (dst) and deg_out (src) ============
__global__ __launch_bounds__(256) void k_build2(const uint32_t* __restrict__ tempD,
        const uint16_t* __restrict__ tempS, const int* __restrict__ scan,
        int B, int C, int shift, int E, int N,
        int* __restrict__ row_off, int* __restrict__ csr, int* __restrict__ deg_out){
    __shared__ int cnt[MAXB];
    __shared__ int offl[MAXB];
    int b = blockIdx.x, t = threadIdx.x;
    int range = 1<<shift, nb0 = b<<shift;
    int seg0 = scan[(size_t)b*C];
    int seg1 = (b+1<B) ? scan[(size_t)(b+1)*C] : E;
    for (int i=t;i<range;i+=256) cnt[i]=0;
    __syncthreads();
    for (int i=seg0+t; i<seg1; i+=256)
        atomicAdd(&cnt[tempD[i]>>20], 1);
    __syncthreads();
    if (t==0){ int run=0; for (int i=0;i<range;i++){ offl[i]=run; run+=cnt[i]; } }
    __syncthreads();
    for (int i=t;i<range;i+=256){
        int node = nb0+i;
        if (node < N) row_off[node] = seg0 + offl[i];
    }
    if (b==B-1 && t==0) row_off[N] = E;
    for (int i=t;i<range;i+=256) cnt[i] = offl[i];
    __syncthreads();
    for (int i=seg0+t; i<seg1; i+=256){
        uint32_t v = tempD[i];
        int p = atomicAdd(&cnt[v>>20], 1);
        csr[seg0 + p] = (int)(v & 0xFFFFFu);
    }
    __syncthreads();
    int sg0 = scan[(size_t)(B+b)*C] - E;
    int sg1 = ((b+1<B) ? scan[(size_t)(B+b+1)*C] : 2*E) - E;
    for (int i=t;i<range;i+=256) cnt[i]=0;
    __syncthreads();
    for (int i=sg0+t; i<sg1; i+=256)
        atomicAdd(&cnt[(int)tempS[i] - nb0], 1);
    __syncthreads();
    for (int i=t;i<range;i+=256){
        int node = nb0+i;
        if (node < N) deg_out[node] = cnt[i];
    }
}

// ============ GEMM (swapped-operand MFMA) -> fp8 output ============
__global__ __launch_bounds__(256) void k_gemm(const void* __restrict__ A,
        const uint16_t* __restrict__ Wf, const int* __restrict__ deg_out,
        uint8_t* __restrict__ out8, int nrows, int amode){
    int t = threadIdx.x;
    int wave = t>>6, lane = t&63, quad = lane>>4, low = lane&15;

    int rowA  = blockIdx.x*64 + wave*16 + low;
    int rowAc = min(rowA, nrows-1);

    bf16x8 ah[4];
    if (amode){
        const uint16_t* arow = (const uint16_t*)A + (size_t)rowAc*FD;
        #pragma unroll
        for (int kk=0;kk<4;kk++)
            ah[kk] = *(const bf16x8*)(arow + kk*32 + quad*8);
    } else {
        const float* arow = (const float*)A + (size_t)rowAc*FD;
        #pragma unroll
        for (int kk=0;kk<4;kk++){
            f32x4 f0 = *(const f32x4*)(arow + kk*32 + quad*8);
            f32x4 f1 = *(const f32x4*)(arow + kk*32 + quad*8 + 4);
            #pragma unroll
            for (int j=0;j<4;j++) ah[kk][j]   = (short)f2bf(f0[j]);
            #pragma unroll
            for (int j=0;j<4;j++) ah[kk][j+4] = (short)f2bf(f1[j]);
        }
    }

    f32x4 acc[8];
    #pragma unroll
    for (int n=0;n<8;n++) acc[n] = (f32x4){0.f,0.f,0.f,0.f};

    #pragma unroll
    for (int kk=0;kk<4;kk++){
        #pragma unroll
        for (int n=0;n<8;n++){
            bf16x8 bh = *(const bf16x8*)(Wf + ((size_t)((kk*8+n)*64 + lane))*8);
            acc[n] = __builtin_amdgcn_mfma_f32_16x16x32_bf16(bh, ah[kk], acc[n], 0, 0, 0);
        }
    }

    if (rowA < nrows){
        float sc = rsqrtf((float)max(deg_out[rowA], 1));
        uint8_t* orow = out8 + (size_t)rowA*FD;
        #pragma unroll
        for (int n=0;n<8;n++){
            uint32_t pk = pk4fp8(acc[n][0]*sc, acc[n][1]*sc, acc[n][2]*sc, acc[n][3]*sc);
            *(uint32_t*)(orow + n*16 + quad*4) = pk;
        }
    }
}

// ============ SpMM: quarter-wave per node, 8B/lane, DEPTH-8 batching ============
// 16 lanes cover one 128B fp8 row; each quarter owns its own node. 8 row
// gathers in flight per quarter (32/wave): all shfls issued, then all loads,
// then masked accumulate.
__global__ __launch_bounds__(256) void k_spmm(const uint8_t* __restrict__ tmp8,
        const int* __restrict__ row_off, const int* __restrict__ csr_src,
        const float* __restrict__ bias, uint16_t* __restrict__ hout, int N){
    int tid = threadIdx.x;
    int node = blockIdx.x*16 + (tid>>4);
    int l  = tid & 15;           // lane within quarter
    int qb = (tid & 63) & 48;    // quarter base within the wave
    if (node >= N) return;
    int e0 = row_off[node], e1 = row_off[node+1];
    const uint2* tp = (const uint2*)tmp8;      // row = 16 x uint2 (128 B)
    f32x2 a01={0.f,0.f}, a23={0.f,0.f}, a45={0.f,0.f}, a67={0.f,0.f};
    for (int base = e0; base < e1; base += 16){
        int my = 0;
        if (base + l < e1) my = csr_src[base + l];
        int cnt = min(16, e1 - base);
        for (int j0 = 0; j0 < cnt; j0 += 8){
            int ss[8];
            #pragma unroll
            for (int k=0;k<8;k++)
                ss[k] = __shfl(my, qb + min(j0 + k, cnt-1));
            uint2 p[8];
            #pragma unroll
            for (int k=0;k<8;k++)
                p[k] = tp[(size_t)ss[k]*16 + l];
            #pragma unroll
            for (int k=0;k<8;k++){
                if (j0 + k < cnt){
                    a01 += fp8lo2f(p[k].x); a23 += fp8hi2f(p[k].x);
                    a45 += fp8lo2f(p[k].y); a67 += fp8hi2f(p[k].y);
                }
            }
        }
    }
    float isq = rsqrtf((float)max(e1 - e0, 1));
    f32x4 b0 = *(const f32x4*)(bias + l*8);
    f32x4 b1 = *(const f32x4*)(bias + l*8 + 4);
    float r0 = fmaxf(a01.x*isq + b0[0], 0.f);
    float r1 = fmaxf(a01.y*isq + b0[1], 0.f);
    float r2 = fmaxf(a23.x*isq + b0[2], 0.f);
    float r3 = fmaxf(a23.y*isq + b0[3], 0.f);
    float r4 = fmaxf(a45.x*isq + b1[0], 0.f);
    float r5 = fmaxf(a45.y*isq + b1[1], 0.f);
    float r6 = fmaxf(a67.x*isq + b1[2], 0.f);
    float r7 = fmaxf(a67.y*isq + b1[3], 0.f);
    uint4 o;
    o.x = (uint32_t)f2bf(r0) | ((uint32_t)f2bf(r1) << 16);
    o.y = (uint32_t)f2bf(r2) | ((uint32_t)f2bf(r3) << 16);
    o.z = (uint32_t)f2bf(r4) | ((uint32_t)f2bf(r5) << 16);
    o.w = (uint32_t)f2bf(r6) | ((uint32_t)f2bf(r7) << 16);
    *(uint4*)(hout + (size_t)node*FD + l*8) = o;
}

// ============ pool: batched loads, run-length accumulate ============
__global__ __launch_bounds__(256) void k_pool(const uint16_t* __restrict__ h,
        const int* __restrict__ n2g, int N, float* __restrict__ pool){
    __shared__ float sacc[NG*FD];
    int t = threadIdx.x;
    for (int i = t; i < NG*FD; i += 256) sacc[i] = 0.f;
    __syncthreads();
    int fp = t & 63;
    int no = t >> 6;
    const uint32_t* hp = (const uint32_t*)h;
    int base = blockIdx.x * 64;
    int gg[16]; uint32_t pv[16];
    #pragma unroll
    for (int i = 0; i < 16; i++){
        int node = base + i*4 + no;
        int nc = min(node, N-1);
        gg[i] = n2g[nc];
        uint32_t v = hp[(size_t)nc*64 + fp];
        pv[i] = (node < N) ? v : 0u;
    }
    float r0 = 0.f, r1 = 0.f; int rg = gg[0];
    #pragma unroll
    for (int i = 0; i < 16; i++){
        if (gg[i] != rg){
            atomicAdd(&sacc[rg*FD + fp*2],     r0);
            atomicAdd(&sacc[rg*FD + fp*2 + 1], r1);
            r0 = r1 = 0.f; rg = gg[i];
        }
        r0 += bf2f((uint16_t)(pv[i] & 0xffff));
        r1 += bf2f((uint16_t)(pv[i] >> 16));
    }
    atomicAdd(&sacc[rg*FD + fp*2],     r0);
    atomicAdd(&sacc[rg*FD + fp*2 + 1], r1);
    __syncthreads();
    for (int i = t; i < NG*FD; i += 256){
        float v = sacc[i];
        if (v != 0.f) atomicAdd(&pool[i], v);
    }
}

// ============ mean, linear, softmax -> 80 f32 ============
__global__ __launch_bounds__(128) void k_final(const float* __restrict__ pool,
        const int* __restrict__ n2g, int N, const float* __restrict__ Wl,
        const float* __restrict__ bl, float* __restrict__ out){
    __shared__ int ub[NG+1];
    __shared__ float logits[NG][NC];
    int t = threadIdx.x;
    if (t <= NG){
        int lo = 0, hi = N;
        while (lo < hi){ int mid = (lo+hi)>>1; if (n2g[mid] < t) lo = mid+1; else hi = mid; }
        ub[t] = lo;
    }
    __syncthreads();
    if (t < NG*NC){
        int g = t/NC, c = t%NC;
        float cnt = (float)max(ub[g+1]-ub[g], 1);
        float inv = 1.f/cnt;
        float acc = bl[c];
        for (int d=0; d<FD; d++)
            acc += pool[g*FD+d]*inv * Wl[d*NC+c];
        logits[g][c] = acc;
    }
    __syncthreads();
    if (t < NG*NC){
        int g = t/NC, c = t%NC;
        float m = -1e30f;
        for (int i=0;i<NC;i++) m = fmaxf(m, logits[g][i]);
        float ssum = 0.f;
        for (int i=0;i<NC;i++) ssum += expf(logits[g][i]-m);
        out[t] = expf(logits[g][c]-m)/ssum;
    }
}

extern "C" void kernel_launch(void* const* d_in, const int* in_sizes, int n_in,
                              void* d_out, int out_size, void* d_ws, size_t ws_size,
                              hipStream_t stream) {
    const float* x   = (const float*)d_in[0];
    const int*   ei  = (const int*)d_in[1];
    const int*   n2g = (const int*)d_in[2];
    const float* W1  = (const float*)d_in[3];
    const float* b1  = (const float*)d_in[4];
    const float* W2  = (const float*)d_in[5];
    const float* b2  = (const float*)d_in[6];
    const float* Wl  = (const float*)d_in[7];
    const float* bl  = (const float*)d_in[8];
    float* outp = (float*)d_out;

    int N = in_sizes[2];
    int E = in_sizes[1] / 2;

    int shift = 6;
    while ((((N + (1<<shift) - 1) >> shift) > MAXB) && shift < 10) shift++;
    int B = (N + (1<<shift) - 1) >> shift;
    int C = (E + CHUNK - 1) / CHUNK;
    int M = 2*B*C;
    int nscan = (M + STILE - 1) / STILE;   // <= 1024 (state array)

    char* w = (char*)d_ws;
    size_t off = 0;
    auto alloc = [&](size_t bytes)->char*{ char* p = w + off; off += (bytes + 255) & ~(size_t)255; return p; };
    float*    pool    = (float*)alloc((size_t)NG*FD*4);
    unsigned long long* state = (unsigned long long*)alloc(1024*8);
    int*      counters= (int*)alloc(8*4);       // [0]=scan ticket
    int*      deg_out = (int*)alloc((size_t)N*4);
    int*      row_off = (int*)alloc((size_t)(N+1)*4);
    int*      csr     = (int*)alloc((size_t)E*4);
    uint16_t* Wf1     = (uint16_t*)alloc(16384*2);
    uint16_t* Wf2     = (uint16_t*)alloc(16384*2);
    uint8_t*  tmp8    = (uint8_t*)alloc((size_t)N*FD);
    uint16_t* hb      = (uint16_t*)alloc((size_t)N*FD*2);
    (void)ws_size;
    // aliases (live only during CSR build, before tmp8/hb are written)
    uint32_t* tempD = (uint32_t*)tmp8;                      // E*4 <= N*FD
    uint16_t* tempS = (uint16_t*)(tmp8 + (size_t)E*4);      // +E*2
    int* cnt = (int*)hb;                                    // M*4 <= N*FD*2

    k_prep   <<<128 + C, 256, 0, stream>>>(W1, W2, Wf1, Wf2, ei, E, B, C, shift,
                                           cnt, pool, state, counters);
    k_scan   <<<nscan, 256, 0, stream>>>(cnt, M, state, &counters[0]);
    k_scatter<<<C, 256, 0, stream>>>(ei, E, B, C, shift, cnt, tempD, tempS);
    k_build2 <<<B, 256, 0, stream>>>(tempD, tempS, cnt, B, C, shift, E, N, row_off, csr, deg_out);

    int gb = (N + 63)/64;
    int sb = (N + 15)/16;
    int pb = (N + 63)/64;
    k_gemm  <<<gb, 256, 0, stream>>>(x,  Wf1, deg_out, tmp8, N, 0);
    k_spmm  <<<sb, 256, 0, stream>>>(tmp8, row_off, csr, b1, hb, N);
    k_gemm  <<<gb, 256, 0, stream>>>(hb, Wf2, deg_out, tmp8, N, 1);
    k_spmm  <<<sb, 256, 0, stream>>>(tmp8, row_off, csr, b2, hb, N);
    k_pool  <<<pb, 256, 0, stream>>>(hb, n2g, N, pool);
    k_final <<<1,  128, 0, stream>>>(pool, n2g, N, Wl, bl, outp);
}